// Round 9
// baseline (460.904 us; speedup 1.0000x reference)
//
#include <hip/hip_runtime.h>
#include <hip/hip_bf16.h>
#include <math.h>

#define NB 8
#define NN 4096
#define KK 16
#define MM (NB*NN)
#define CH 32
#define SLOTS 17
#define NCLS 40
#define BIG 3.0e38f
#define CAP 324   // survivor capacity; P(overflow) ~ 1e-8 per query

// Weight table offsets (floats)
#define OW1A 0
#define OB1A 128
#define OW1B 160
#define OB1B 1184
#define OW2A 1216
#define OB2A 2368
#define OW2B 2400
#define OB2B 3424
#define OWC  3456
#define OBC  4736
#define NWTS 4776

// Module-global scratch (~11 MB): no assumptions about ws_size.
__device__ float4 g_pos4[MM];
__device__ float4 g_nrm4[MM];
__device__ int    g_nbr[MM*KK];
__device__ float  g_u[MM*CH];
__device__ float  g_x2[MM*CH];
__device__ float  g_wts[NWTS];
__device__ int    g_isf32;

__device__ __forceinline__ float bf(const __hip_bfloat16 x) { return __bfloat162float(x); }

// dual-dtype load: element i of array that is either float32 or bf16
__device__ __forceinline__ float ldf(const void* p, int i, bool f32) {
  return f32 ? ((const float*)p)[i] : bf(((const __hip_bfloat16*)p)[i]);
}

__device__ __forceinline__ float angf(float ax, float ay, float az,
                                      float bx, float by, float bz) {
  float cx = ay*bz - az*by;
  float cy = az*bx - ax*bz;
  float cz = ax*by - ay*bx;
  float s  = cx*cx + cy*cy + cz*cz;
  float cn = s > 0.f ? sqrtf(s) : 0.f;
  float d  = ax*bx + ay*by + az*bz;
  return (cn > 0.f || d != 0.f) ? atan2f(cn, d) : 0.f;
}

__device__ __forceinline__ void ppf4(const float4 pi, const float4 ni,
                                     const float4 pj, const float4 nj, float* f) {
  float px = pj.x - pi.x, py = pj.y - pi.y, pz = pj.z - pi.z;
  float s = px*px + py*py + pz*pz;
  f[0] = s > 0.f ? sqrtf(s) : 0.f;
  f[1] = angf(ni.x, ni.y, ni.z, px, py, pz);
  f[2] = angf(nj.x, nj.y, nj.z, px, py, pz);
  f[3] = angf(ni.x, ni.y, ni.z, nj.x, nj.y, nj.z);
}

// ---------------- wprep: parallel dtype vote + convert weights to fp32 ----------------
__global__ __launch_bounds__(256) void wprep_kernel(
    const void* nrm, const void* w1a, const void* b1a, const void* w1b,
    const void* b1b, const void* w2a, const void* b2a, const void* w2b,
    const void* b2b, const void* wc, const void* bc) {
  __shared__ int sflag;
  const int tid = threadIdx.x;
  if (tid < 64) {
    const float* nf = (const float*)nrm;
    const __hip_bfloat16* nh = (const __hip_bfloat16*)nrm;
    float x = nf[3*tid], y = nf[3*tid+1], z = nf[3*tid+2];
    float ss = x*x + y*y + z*z;
    bool okf = (ss > 0.98f && ss < 1.02f);
    float a = bf(nh[3*tid]), b2 = bf(nh[3*tid+1]), c2 = bf(nh[3*tid+2]);
    float sb = a*a + b2*b2 + c2*c2;
    bool okb = (sb > 0.95f && sb < 1.05f);
    unsigned long long mf = __ballot(okf), mb = __ballot(okb);
    if (tid == 0) {
      sflag = (__popcll(mf) >= __popcll(mb)) ? 1 : 0;
      g_isf32 = sflag;
    }
  }
  __syncthreads();
  const bool f32 = sflag != 0;
  for (int i = tid; i < 128;  i += 256) g_wts[OW1A + i] = ldf(w1a, i, f32);
  for (int i = tid; i < 32;   i += 256) g_wts[OB1A + i] = ldf(b1a, i, f32);
  for (int i = tid; i < 1024; i += 256) g_wts[OW1B + i] = ldf(w1b, i, f32);
  for (int i = tid; i < 32;   i += 256) g_wts[OB1B + i] = ldf(b1b, i, f32);
  for (int i = tid; i < 1152; i += 256) g_wts[OW2A + i] = ldf(w2a, i, f32);
  for (int i = tid; i < 32;   i += 256) g_wts[OB2A + i] = ldf(b2a, i, f32);
  for (int i = tid; i < 1024; i += 256) g_wts[OW2B + i] = ldf(w2b, i, f32);
  for (int i = tid; i < 32;   i += 256) g_wts[OB2B + i] = ldf(b2b, i, f32);
  for (int i = tid; i < 1280; i += 256) g_wts[OWC  + i] = ldf(wc,  i, f32);
  for (int i = tid; i < 40;   i += 256) g_wts[OBC  + i] = ldf(bc,  i, f32);
}

// ---------------- prep: inputs -> float4 (pos.w = |p|^2 f32, filter only) ----------------
__global__ __launch_bounds__(256) void prep_kernel(const void* __restrict__ pos,
                                                   const void* __restrict__ nrm) {
  const bool f32 = g_isf32 != 0;
  int i = blockIdx.x*256 + threadIdx.x;
  float x = ldf(pos, 3*i, f32), y = ldf(pos, 3*i+1, f32), z = ldf(pos, 3*i+2, f32);
  float sq = x*x + y*y + z*z;
  g_pos4[i] = make_float4(x, y, z, sq);
  float a = ldf(nrm, 3*i, f32), b = ldf(nrm, 3*i+1, f32), c = ldf(nrm, 3*i+2, f32);
  g_nrm4[i] = make_float4(a, b, c, 0.f);
}

// ---------------- kNN: 4 queries per wave, tile-free (L2-direct), no barriers ----------
// Candidates are read straight from g_pos4 (64 KB/batch, L2-resident, coalesced;
// every loaded candidate feeds 4 independent d2 chains). Pass 1: 16 residue-class
// mins per query (class = cand&15 = lane&15); T = max of class mins => >=16
// distinct non-self candidates <= T. Tf adds an absolute margin >> f32 error
// (also absorbs pass1/pass2 contraction drift). Pass 2 recomputes d2 and collects
// survivors (~54/query) into wave-PRIVATE LDS lists via per-query atomics.
// Then per query: f64 rescore (numpy-exact association) + exact lexicographic
// (d2_f64, idx) rank. No __syncthreads anywhere: all LDS is wave-private;
// intra-wave ordering via program order + __threadfence_block().
__global__ __launch_bounds__(256) void knn_kernel() {
  __shared__ int    ilst[16][CAP];     // 20736 B  (4 waves x 4 queries)
  __shared__ double dlst[4][CAP];      // 10368 B  (per-wave rescore buffer)
  __shared__ int    cnt[16];
  const int tid  = threadIdx.x;
  const int w    = tid >> 6, lane = tid & 63;
  const int blk  = blockIdx.x;
  const int b    = blk >> 8;                       // 256 blocks per batch
  const int qb   = ((blk & 255) << 4) | (w << 2);  // first of this wave's 4 queries
  const float4* bp = g_pos4 + b*NN;
  const float4 q0 = bp[qb], q1 = bp[qb+1], q2 = bp[qb+2], q3 = bp[qb+3];

  // ---- pass 1: class mins for 4 queries ----
  float m0 = BIG, m1 = BIG, m2 = BIG, m3 = BIG;
  for (int it = 0; it < 64; ++it) {
    int cand = it*64 + lane;
    float4 o = bp[cand];
    float d0 = (q0.w + o.w) - 2.f*(q0.x*o.x + q0.y*o.y + q0.z*o.z);
    float d1 = (q1.w + o.w) - 2.f*(q1.x*o.x + q1.y*o.y + q1.z*o.z);
    float d2 = (q2.w + o.w) - 2.f*(q2.x*o.x + q2.y*o.y + q2.z*o.z);
    float d3 = (q3.w + o.w) - 2.f*(q3.x*o.x + q3.y*o.y + q3.z*o.z);
    if (cand == qb  ) d0 = BIG;
    if (cand == qb+1) d1 = BIG;
    if (cand == qb+2) d2 = BIG;
    if (cand == qb+3) d3 = BIG;
    m0 = fminf(m0, d0); m1 = fminf(m1, d1); m2 = fminf(m2, d2); m3 = fminf(m3, d3);
  }
  // merge lanes sharing a class (class = lane&15), then max over the 16 classes
  float Tf[4];
  {
    float mm[4] = {m0, m1, m2, m3};
    #pragma unroll
    for (int qq = 0; qq < 4; ++qq) {
      float lm = mm[qq];
      lm = fminf(lm, __shfl_xor(lm, 16));
      lm = fminf(lm, __shfl_xor(lm, 32));
      float T = lm;
      #pragma unroll
      for (int d = 1; d < 64; d <<= 1) T = fmaxf(T, __shfl_xor(T, d));
      Tf[qq] = T + 2e-5f + 1e-5f*fabsf(T);   // absolute margin >> f32 d2 error
    }
  }

  if (lane < 4) cnt[(w<<2) | lane] = 0;      // wave-private counters
  __threadfence_block();

  // ---- pass 2: recompute + sparse per-query collect (wave-private lists) ----
  for (int it = 0; it < 64; ++it) {
    int cand = it*64 + lane;
    float4 o = bp[cand];
    float d0 = (q0.w + o.w) - 2.f*(q0.x*o.x + q0.y*o.y + q0.z*o.z);
    float d1 = (q1.w + o.w) - 2.f*(q1.x*o.x + q1.y*o.y + q1.z*o.z);
    float d2 = (q2.w + o.w) - 2.f*(q2.x*o.x + q2.y*o.y + q2.z*o.z);
    float d3 = (q3.w + o.w) - 2.f*(q3.x*o.x + q3.y*o.y + q3.z*o.z);
    if (d0 <= Tf[0] && cand != qb) {
      int p = atomicAdd(&cnt[(w<<2)|0], 1);
      if (p < CAP) ilst[(w<<2)|0][p] = cand;
    }
    if (d1 <= Tf[1] && cand != qb+1) {
      int p = atomicAdd(&cnt[(w<<2)|1], 1);
      if (p < CAP) ilst[(w<<2)|1][p] = cand;
    }
    if (d2 <= Tf[2] && cand != qb+2) {
      int p = atomicAdd(&cnt[(w<<2)|2], 1);
      if (p < CAP) ilst[(w<<2)|2][p] = cand;
    }
    if (d3 <= Tf[3] && cand != qb+3) {
      int p = atomicAdd(&cnt[(w<<2)|3], 1);
      if (p < CAP) ilst[(w<<2)|3][p] = cand;
    }
  }
  __threadfence_block();

  // ---- per query: f64 rescore (numpy-exact) + exact (d2_f64, idx) rank ----
  #pragma unroll 1
  for (int qq = 0; qq < 4; ++qq) {
    const int qi = qb + qq;
    const int m = min(cnt[(w<<2)|qq], CAP);
    const float4 q = bp[qi];
    const double mx = (double)q.x, my_ = (double)q.y, mz = (double)q.z;
    const double sqme = (mx*mx + my_*my_) + mz*mz;
    for (int e = lane; e < m; e += 64) {
      int ci = ilst[(w<<2)|qq][e];
      float4 o = bp[ci];
      double ox = (double)o.x, oy = (double)o.y, oz = (double)o.z;
      double sqo = (ox*ox + oy*oy) + oz*oz;
      double dt  = (mx*ox + my_*oy) + mz*oz;
      dlst[w][e] = (sqme + sqo) - 2.0*dt;
    }
    __threadfence_block();
    for (int e = lane; e < m; e += 64) {
      double myd = dlst[w][e];
      int myi = ilst[(w<<2)|qq][e];
      int rank = 0;
      for (int o = 0; o < m; ++o) {          // broadcast LDS reads
        double od = dlst[w][o];
        int oi = ilst[(w<<2)|qq][o];
        rank += (od < myd) || (od == myd && oi < myi);
      }
      if (rank < KK) g_nbr[(b*NN + qi)*KK + rank] = b*NN + myi;
    }
    __threadfence_block();                   // dlst reused next qq
  }
}

// ---------------- conv1: 8 nodes/block, fused u = relu(max(msg1)) @ w2a[0:32] ----------------
__global__ __launch_bounds__(256) void conv1_kernel() {
  __shared__ __align__(16) float fe[136][4];
  __shared__ __align__(16) float h1s[8*SLOTS*CH];
  __shared__ __align__(16) float xs[8][CH];
  const int tid = threadIdx.x;
  const int c = tid & 31;
  const int node0 = blockIdx.x << 3;
  float w1a_c[4], w1b_c[32], w2a_c[32];
  #pragma unroll
  for (int f = 0; f < 4; ++f)  w1a_c[f] = g_wts[OW1A + f*CH + c];
  #pragma unroll
  for (int k = 0; k < 32; ++k) w1b_c[k] = g_wts[OW1B + k*CH + c];
  #pragma unroll
  for (int k = 0; k < 32; ++k) w2a_c[k] = g_wts[OW2A + k*CH + c];
  const float b1a_c = g_wts[OB1A + c], b1b_c = g_wts[OB1B + c];

  if (tid < 136) {
    int ns = tid / 17, slot = tid - ns*17;
    int i = node0 + ns;
    int j = (slot < KK) ? g_nbr[i*KK + slot] : i;   // slot 16 = self-loop
    ppf4(g_pos4[i], g_nrm4[i], g_pos4[j], g_nrm4[j], fe[tid]);
  }
  __syncthreads();
  #pragma unroll
  for (int it = 0; it < 17; ++it) {
    int idx = it*256 + tid;                   // (e, c) with c == tid&31
    int e = idx >> 5;
    float4 f4 = *(const float4*)fe[e];
    float h = b1a_c + f4.x*w1a_c[0] + f4.y*w1a_c[1] + f4.z*w1a_c[2] + f4.w*w1a_c[3];
    h1s[idx] = fmaxf(h, 0.f);
  }
  __syncthreads();
  const int ns = tid >> 5;
  const int i  = node0 + ns;
  float acc = -BIG;
  #pragma unroll
  for (int slot = 0; slot < SLOTS; ++slot) {
    const float* hr = &h1s[(ns*SLOTS + slot)*CH];
    float msg = b1b_c;
    #pragma unroll
    for (int k4 = 0; k4 < 8; ++k4) {
      float4 h4 = *(const float4*)(hr + 4*k4);
      msg += h4.x*w1b_c[4*k4] + h4.y*w1b_c[4*k4+1] + h4.z*w1b_c[4*k4+2] + h4.w*w1b_c[4*k4+3];
    }
    acc = fmaxf(acc, msg);
  }
  xs[ns][c] = fmaxf(acc, 0.f);                // x1 = relu(segment_max)
  __syncthreads();
  float uu = 0.f;
  #pragma unroll
  for (int k4 = 0; k4 < 8; ++k4) {
    float4 x4 = *(const float4*)&xs[ns][4*k4];
    uu += x4.x*w2a_c[4*k4] + x4.y*w2a_c[4*k4+1] + x4.z*w2a_c[4*k4+2] + x4.w*w2a_c[4*k4+3];
  }
  g_u[i*CH + c] = uu;                         // u = x1 @ w2a[0:32,:]
}

// ---------------- conv2 ----------------
__global__ __launch_bounds__(256) void conv2_kernel() {
  __shared__ __align__(16) float fe[136][4];
  __shared__ int jn[136];
  __shared__ __align__(16) float h2s[8*SLOTS*CH];
  const int tid = threadIdx.x;
  const int c = tid & 31;
  const int node0 = blockIdx.x << 3;
  float w2aL_c[4], w2b_c[32];
  #pragma unroll
  for (int f = 0; f < 4; ++f)  w2aL_c[f] = g_wts[OW2A + (CH + f)*CH + c];
  #pragma unroll
  for (int k = 0; k < 32; ++k) w2b_c[k] = g_wts[OW2B + k*CH + c];
  const float b2a_c = g_wts[OB2A + c], b2b_c = g_wts[OB2B + c];

  if (tid < 136) {
    int ns = tid / 17, slot = tid - ns*17;
    int i = node0 + ns;
    int j = (slot < KK) ? g_nbr[i*KK + slot] : i;
    jn[tid] = j;
    ppf4(g_pos4[i], g_nrm4[i], g_pos4[j], g_nrm4[j], fe[tid]);
  }
  __syncthreads();
  #pragma unroll
  for (int it = 0; it < 17; ++it) {
    int idx = it*256 + tid;
    int e = idx >> 5;
    float4 f4 = *(const float4*)fe[e];
    float uv = g_u[jn[e]*CH + c];             // x_j @ w2a[0:32] precomputed
    float h = b2a_c + uv + f4.x*w2aL_c[0] + f4.y*w2aL_c[1] + f4.z*w2aL_c[2] + f4.w*w2aL_c[3];
    h2s[idx] = fmaxf(h, 0.f);
  }
  __syncthreads();
  const int ns = tid >> 5;
  float acc = -BIG;
  #pragma unroll
  for (int slot = 0; slot < SLOTS; ++slot) {
    const float* hr = &h2s[(ns*SLOTS + slot)*CH];
    float msg = b2b_c;
    #pragma unroll
    for (int k4 = 0; k4 < 8; ++k4) {
      float4 h4 = *(const float4*)(hr + 4*k4);
      msg += h4.x*w2b_c[4*k4] + h4.y*w2b_c[4*k4+1] + h4.z*w2b_c[4*k4+2] + h4.w*w2b_c[4*k4+3];
    }
    acc = fmaxf(acc, msg);
  }
  g_x2[(node0 + ns)*CH + c] = fmaxf(acc, 0.f);
}

// ---------------- pool + head (float32 output) ----------------
__global__ __launch_bounds__(256) void pool_kernel(float* __restrict__ out) {
  __shared__ float red[8][CH];
  const int g = blockIdx.x;
  const int c = threadIdx.x & 31, chunk = threadIdx.x >> 5;
  const float* base = g_x2 + (size_t)(g*NN + chunk*512)*CH + c;
  float mx = -BIG;
  for (int n = 0; n < 512; ++n) mx = fmaxf(mx, base[n*CH]);
  red[chunk][c] = mx;
  __syncthreads();
  if (threadIdx.x < CH) {
    float m2 = red[0][c];
    #pragma unroll
    for (int r = 1; r < 8; ++r) m2 = fmaxf(m2, red[r][c]);
    red[0][c] = m2;
  }
  __syncthreads();
  if (threadIdx.x < NCLS) {
    int co = threadIdx.x;
    float s = g_wts[OBC + co];
    #pragma unroll
    for (int f = 0; f < CH; ++f) s += red[0][f] * g_wts[OWC + f*NCLS + co];
    out[g*NCLS + co] = s;                     // float32 out (reference dtype)
  }
}

extern "C" void kernel_launch(void* const* d_in, const int* in_sizes, int n_in,
                              void* d_out, int out_size, void* d_ws, size_t ws_size,
                              hipStream_t stream) {
  const void* pos = d_in[0];
  const void* nrm = d_in[1];
  // d_in[2] = batch (int32) -- unused, batches are uniform
  const void* w1a = d_in[3];
  const void* b1a = d_in[4];
  const void* w1b = d_in[5];
  const void* b1b = d_in[6];
  const void* w2a = d_in[7];
  const void* b2a = d_in[8];
  const void* w2b = d_in[9];
  const void* b2b = d_in[10];
  const void* wc  = d_in[11];
  const void* bc  = d_in[12];

  wprep_kernel<<<1,       256, 0, stream>>>(nrm, w1a, b1a, w1b, b1b, w2a, b2a, w2b, b2b, wc, bc);
  prep_kernel <<<MM/256,  256, 0, stream>>>(pos, nrm);
  knn_kernel  <<<MM/16,   256, 0, stream>>>();
  conv1_kernel<<<MM/8,    256, 0, stream>>>();
  conv2_kernel<<<MM/8,    256, 0, stream>>>();
  pool_kernel <<<NB,      256, 0, stream>>>((float*)d_out);
}

// Round 11
// 343.623 us; speedup vs baseline: 1.3413x; 1.3413x over previous
//
#include <hip/hip_runtime.h>
#include <hip/hip_bf16.h>
#include <math.h>

#define NB 8
#define NN 4096
#define KK 16
#define MM (NB*NN)
#define CH 32
#define SLOTS 17
#define NCLS 40
#define BIG 3.0e38f
#define CAP 324   // survivor capacity; P(overflow) negligible

// Weight table offsets (floats)
#define OW1A 0
#define OB1A 128
#define OW1B 160
#define OB1B 1184
#define OW2A 1216
#define OB2A 2368
#define OW2B 2400
#define OB2B 3424
#define OWC  3456
#define OBC  4736
#define NWTS 4776

typedef __fp16 h2f __attribute__((ext_vector_type(2)));

// Module-global scratch (~11 MB): no assumptions about ws_size.
__device__ float4 g_pos4[MM];
__device__ float4 g_nrm4[MM];
__device__ int    g_nbr[MM*KK];
__device__ float  g_u[MM*CH];
__device__ float  g_x2[MM*CH];
__device__ float  g_wts[NWTS];
__device__ unsigned int g_gmax[NB*CH];
__device__ int    g_isf32;

__device__ __forceinline__ float bf(const __hip_bfloat16 x) { return __bfloat162float(x); }

__device__ __forceinline__ float ldf(const void* p, int i, bool f32) {
  return f32 ? ((const float*)p)[i] : bf(((const __hip_bfloat16*)p)[i]);
}

__device__ __forceinline__ float angf(float ax, float ay, float az,
                                      float bx, float by, float bz) {
  float cx = ay*bz - az*by;
  float cy = az*bx - ax*bz;
  float cz = ax*by - ay*bx;
  float s  = cx*cx + cy*cy + cz*cz;
  float cn = s > 0.f ? sqrtf(s) : 0.f;
  float d  = ax*bx + ay*by + az*bz;
  return (cn > 0.f || d != 0.f) ? atan2f(cn, d) : 0.f;
}

__device__ __forceinline__ void ppf4(const float4 pi, const float4 ni,
                                     const float4 pj, const float4 nj, float* f) {
  float px = pj.x - pi.x, py = pj.y - pi.y, pz = pj.z - pi.z;
  float s = px*px + py*py + pz*pz;
  f[0] = s > 0.f ? sqrtf(s) : 0.f;
  f[1] = angf(ni.x, ni.y, ni.z, px, py, pz);
  f[2] = angf(nj.x, nj.y, nj.z, px, py, pz);
  f[3] = angf(ni.x, ni.y, ni.z, nj.x, nj.y, nj.z);
}

// ---------------- wprep: parallel dtype vote + weights->fp32 + zero g_gmax ----------------
__global__ __launch_bounds__(256) void wprep_kernel(
    const void* nrm, const void* w1a, const void* b1a, const void* w1b,
    const void* b1b, const void* w2a, const void* b2a, const void* w2b,
    const void* b2b, const void* wc, const void* bc) {
  __shared__ int sflag;
  const int tid = threadIdx.x;
  if (tid < 64) {
    const float* nf = (const float*)nrm;
    const __hip_bfloat16* nh = (const __hip_bfloat16*)nrm;
    float x = nf[3*tid], y = nf[3*tid+1], z = nf[3*tid+2];
    float ss = x*x + y*y + z*z;
    bool okf = (ss > 0.98f && ss < 1.02f);
    float a = bf(nh[3*tid]), b2 = bf(nh[3*tid+1]), c2 = bf(nh[3*tid+2]);
    float sb = a*a + b2*b2 + c2*c2;
    bool okb = (sb > 0.95f && sb < 1.05f);
    unsigned long long mf = __ballot(okf), mb = __ballot(okb);
    if (tid == 0) {
      sflag = (__popcll(mf) >= __popcll(mb)) ? 1 : 0;
      g_isf32 = sflag;
    }
  }
  __syncthreads();
  const bool f32 = sflag != 0;
  for (int i = tid; i < NB*CH; i += 256) g_gmax[i] = 0u;   // max accumulator (x2 >= 0)
  for (int i = tid; i < 128;  i += 256) g_wts[OW1A + i] = ldf(w1a, i, f32);
  for (int i = tid; i < 32;   i += 256) g_wts[OB1A + i] = ldf(b1a, i, f32);
  for (int i = tid; i < 1024; i += 256) g_wts[OW1B + i] = ldf(w1b, i, f32);
  for (int i = tid; i < 32;   i += 256) g_wts[OB1B + i] = ldf(b1b, i, f32);
  for (int i = tid; i < 1152; i += 256) g_wts[OW2A + i] = ldf(w2a, i, f32);
  for (int i = tid; i < 32;   i += 256) g_wts[OB2A + i] = ldf(b2a, i, f32);
  for (int i = tid; i < 1024; i += 256) g_wts[OW2B + i] = ldf(w2b, i, f32);
  for (int i = tid; i < 32;   i += 256) g_wts[OB2B + i] = ldf(b2b, i, f32);
  for (int i = tid; i < 1280; i += 256) g_wts[OWC  + i] = ldf(wc,  i, f32);
  for (int i = tid; i < 40;   i += 256) g_wts[OBC  + i] = ldf(bc,  i, f32);
}

// ---------------- prep: inputs -> float4 (pos.w = |p|^2 f32, filter only) ----------------
__global__ __launch_bounds__(256) void prep_kernel(const void* __restrict__ pos,
                                                   const void* __restrict__ nrm) {
  const bool f32 = g_isf32 != 0;
  int i = blockIdx.x*256 + threadIdx.x;
  float x = ldf(pos, 3*i, f32), y = ldf(pos, 3*i+1, f32), z = ldf(pos, 3*i+2, f32);
  float sq = x*x + y*y + z*z;
  g_pos4[i] = make_float4(x, y, z, sq);
  float a = ldf(nrm, 3*i, f32), b = ldf(nrm, 3*i+1, f32), c = ldf(nrm, 3*i+2, f32);
  g_nrm4[i] = make_float4(a, b, c, 0.f);
}

// ---------------- kNN: one wave/query, SINGLE tile pass + f16-packed d2 cache ----------
// Streaming pass computes f32 d2 (exact, same formula as before), updates the 16
// residue-class mins, and caches d2 as packed f16 pairs via v_cvt_pkrtz (RTZ:
// positive d2 rounds DOWN, so true top-16 (d2<=T<=Tf) always has cached<=Tf --
// one-sided, no extra margin; f16 false-positives only add survivors, which the
// exact f64 rescore+rank then handles; self: RTZ(3e38)=65504 > Tf => excluded).
// Collect is a register-only sweep (no second staging / ds_read / recompute).
__global__ __launch_bounds__(256, 4) void knn_kernel() {
  __shared__ float4 tile[1024];        // 16384 B
  __shared__ int    ilst[4][CAP];      //  5184 B
  __shared__ double dlst[4][CAP];      // 10368 B
  __shared__ int    cnt[4];
  const int tid  = threadIdx.x;
  const int w    = tid >> 6, lane = tid & 63;
  const int blk  = blockIdx.x;
  const int b    = blk >> 10;                 // 1024 blocks per batch
  const int pib  = ((blk & 1023) << 2) | w;   // point-in-batch (query)
  const float4* bp = g_pos4 + b*NN;
  const float4 me = bp[pib];

  h2f cache[32];
  float lmin0 = BIG, lmin1 = BIG;
  float dprev = 0.f;
  #pragma unroll
  for (int t = 0; t < 4; ++t) {
    #pragma unroll
    for (int k = 0; k < 4; ++k) tile[k*256 + tid] = bp[t*1024 + k*256 + tid];
    __syncthreads();
    #pragma unroll
    for (int r = 0; r < 16; ++r) {
      float4 o  = tile[r*64 + lane];
      int cand  = t*1024 + r*64 + lane;
      float dt  = me.x*o.x + me.y*o.y + me.z*o.z;
      float d2  = (me.w + o.w) - 2.f*dt;
      d2 = (cand == pib) ? BIG : d2;           // exclude self
      if (r & 1) {
        lmin1 = fminf(lmin1, d2);
        cache[t*8 + (r >> 1)] = __builtin_amdgcn_cvt_pkrtz(dprev, d2);
      } else {
        lmin0 = fminf(lmin0, d2);
        dprev = d2;
      }
    }
    __syncthreads();
  }
  float lmin = fminf(lmin0, lmin1);
  // class = lane&15; merge lanes sharing a class, then max over the 16 classes
  lmin = fminf(lmin, __shfl_xor(lmin, 16));
  lmin = fminf(lmin, __shfl_xor(lmin, 32));
  float T = lmin;
  #pragma unroll
  for (int d = 1; d < 64; d <<= 1) T = fmaxf(T, __shfl_xor(T, d));
  const float Tf = T + 2e-5f + 1e-5f*fabsf(T);  // absolute margin >> f32 d2 error

  if (lane == 0) cnt[w] = 0;                    // wave-private; same-wave LDS ordered

  // ---- register-only collect from the f16 cache ----
  #pragma unroll
  for (int i = 0; i < 32; ++i) {
    float d0 = (float)cache[i].x;
    float d1 = (float)cache[i].y;
    if (d0 <= Tf) {
      int p = atomicAdd(&cnt[w], 1);
      if (p < CAP) ilst[w][p] = ((2*i) >> 4)*1024 + ((2*i) & 15)*64 + lane;
    }
    if (d1 <= Tf) {
      int p = atomicAdd(&cnt[w], 1);
      if (p < CAP) ilst[w][p] = ((2*i+1) >> 4)*1024 + ((2*i+1) & 15)*64 + lane;
    }
  }
  const int m = min(cnt[w], CAP);

  // ---- f64 rescore of survivors, numpy-exact association ----
  const double mx = (double)me.x, my_ = (double)me.y, mz = (double)me.z;
  const double sqme = (mx*mx + my_*my_) + mz*mz;
  for (int e = lane; e < m; e += 64) {
    int ci = ilst[w][e];
    float4 o = bp[ci];
    double ox = (double)o.x, oy = (double)o.y, oz = (double)o.z;
    double sqo = (ox*ox + oy*oy) + oz*oz;
    double dt  = (mx*ox + my_*oy) + mz*oz;
    dlst[w][e] = (sqme + sqo) - 2.0*dt;
  }
  for (int e = lane; e < m; e += 64) {
    double myd = dlst[w][e];
    int myi = ilst[w][e];
    int rank = 0;
    for (int o = 0; o < m; ++o) {            // broadcast LDS reads
      double od = dlst[w][o];
      int oi = ilst[w][o];
      rank += (od < myd) || (od == myd && oi < myi);
    }
    if (rank < KK) g_nbr[(b*NN + pib)*KK + rank] = b*NN + myi;
  }
}

// ---------------- conv1: 8 nodes/block, fused u = relu(max(msg1)) @ w2a[0:32] ----------------
__global__ __launch_bounds__(256) void conv1_kernel() {
  __shared__ __align__(16) float fe[136][4];
  __shared__ __align__(16) float h1s[8*SLOTS*CH];
  __shared__ __align__(16) float xs[8][CH];
  const int tid = threadIdx.x;
  const int c = tid & 31;
  const int node0 = blockIdx.x << 3;
  float w1a_c[4], w1b_c[32], w2a_c[32];
  #pragma unroll
  for (int f = 0; f < 4; ++f)  w1a_c[f] = g_wts[OW1A + f*CH + c];
  #pragma unroll
  for (int k = 0; k < 32; ++k) w1b_c[k] = g_wts[OW1B + k*CH + c];
  #pragma unroll
  for (int k = 0; k < 32; ++k) w2a_c[k] = g_wts[OW2A + k*CH + c];
  const float b1a_c = g_wts[OB1A + c], b1b_c = g_wts[OB1B + c];

  if (tid < 136) {
    int ns = tid / 17, slot = tid - ns*17;
    int i = node0 + ns;
    int j = (slot < KK) ? g_nbr[i*KK + slot] : i;   // slot 16 = self-loop
    ppf4(g_pos4[i], g_nrm4[i], g_pos4[j], g_nrm4[j], fe[tid]);
  }
  __syncthreads();
  #pragma unroll
  for (int it = 0; it < 17; ++it) {
    int idx = it*256 + tid;                   // (e, c) with c == tid&31
    int e = idx >> 5;
    float4 f4 = *(const float4*)fe[e];
    float h = b1a_c + f4.x*w1a_c[0] + f4.y*w1a_c[1] + f4.z*w1a_c[2] + f4.w*w1a_c[3];
    h1s[idx] = fmaxf(h, 0.f);
  }
  __syncthreads();
  const int ns = tid >> 5;
  const int i  = node0 + ns;
  float acc = -BIG;
  #pragma unroll
  for (int slot = 0; slot < SLOTS; ++slot) {
    const float* hr = &h1s[(ns*SLOTS + slot)*CH];
    float msg = b1b_c;
    #pragma unroll
    for (int k4 = 0; k4 < 8; ++k4) {
      float4 h4 = *(const float4*)(hr + 4*k4);
      msg += h4.x*w1b_c[4*k4] + h4.y*w1b_c[4*k4+1] + h4.z*w1b_c[4*k4+2] + h4.w*w1b_c[4*k4+3];
    }
    acc = fmaxf(acc, msg);
  }
  xs[ns][c] = fmaxf(acc, 0.f);                // x1 = relu(segment_max)
  __syncthreads();
  float uu = 0.f;
  #pragma unroll
  for (int k4 = 0; k4 < 8; ++k4) {
    float4 x4 = *(const float4*)&xs[ns][4*k4];
    uu += x4.x*w2a_c[4*k4] + x4.y*w2a_c[4*k4+1] + x4.z*w2a_c[4*k4+2] + x4.w*w2a_c[4*k4+3];
  }
  g_u[i*CH + c] = uu;                         // u = x1 @ w2a[0:32,:]
}

// ---------------- conv2 ----------------
__global__ __launch_bounds__(256) void conv2_kernel() {
  __shared__ __align__(16) float fe[136][4];
  __shared__ int jn[136];
  __shared__ __align__(16) float h2s[8*SLOTS*CH];
  const int tid = threadIdx.x;
  const int c = tid & 31;
  const int node0 = blockIdx.x << 3;
  float w2aL_c[4], w2b_c[32];
  #pragma unroll
  for (int f = 0; f < 4; ++f)  w2aL_c[f] = g_wts[OW2A + (CH + f)*CH + c];
  #pragma unroll
  for (int k = 0; k < 32; ++k) w2b_c[k] = g_wts[OW2B + k*CH + c];
  const float b2a_c = g_wts[OB2A + c], b2b_c = g_wts[OB2B + c];

  if (tid < 136) {
    int ns = tid / 17, slot = tid - ns*17;
    int i = node0 + ns;
    int j = (slot < KK) ? g_nbr[i*KK + slot] : i;
    jn[tid] = j;
    ppf4(g_pos4[i], g_nrm4[i], g_pos4[j], g_nrm4[j], fe[tid]);
  }
  __syncthreads();
  #pragma unroll
  for (int it = 0; it < 17; ++it) {
    int idx = it*256 + tid;
    int e = idx >> 5;
    float4 f4 = *(const float4*)fe[e];
    float uv = g_u[jn[e]*CH + c];             // x_j @ w2a[0:32] precomputed
    float h = b2a_c + uv + f4.x*w2aL_c[0] + f4.y*w2aL_c[1] + f4.z*w2aL_c[2] + f4.w*w2aL_c[3];
    h2s[idx] = fmaxf(h, 0.f);
  }
  __syncthreads();
  const int ns = tid >> 5;
  float acc = -BIG;
  #pragma unroll
  for (int slot = 0; slot < SLOTS; ++slot) {
    const float* hr = &h2s[(ns*SLOTS + slot)*CH];
    float msg = b2b_c;
    #pragma unroll
    for (int k4 = 0; k4 < 8; ++k4) {
      float4 h4 = *(const float4*)(hr + 4*k4);
      msg += h4.x*w2b_c[4*k4] + h4.y*w2b_c[4*k4+1] + h4.z*w2b_c[4*k4+2] + h4.w*w2b_c[4*k4+3];
    }
    acc = fmaxf(acc, msg);
  }
  g_x2[(node0 + ns)*CH + c] = fmaxf(acc, 0.f);
}

// ---------------- pmax: 256 blocks, coalesced partial max + device atomicMax ----------------
__global__ __launch_bounds__(256) void pmax_kernel() {
  __shared__ float red[8][CH];
  const int g = blockIdx.x >> 5;              // graph
  const int chunk = blockIdx.x & 31;          // 128 nodes per block
  const int c = threadIdx.x & 31, sub = threadIdx.x >> 5;
  const float* base = g_x2 + (size_t)(g*NN + chunk*128)*CH;
  float mx = 0.f;                             // x2 >= 0 (relu)
  #pragma unroll
  for (int n = 0; n < 16; ++n)
    mx = fmaxf(mx, base[(n*8 + sub)*CH + c]);
  red[sub][c] = mx;
  __syncthreads();
  if (threadIdx.x < CH) {
    float m2 = red[0][c];
    #pragma unroll
    for (int r = 1; r < 8; ++r) m2 = fmaxf(m2, red[r][c]);
    atomicMax(&g_gmax[g*CH + c], __float_as_uint(m2));  // exact for floats >= 0
  }
}

// ---------------- head (float32 output) ----------------
__global__ __launch_bounds__(64) void head_kernel(float* __restrict__ out) {
  const int g = blockIdx.x;
  const int co = threadIdx.x;
  if (co < NCLS) {
    float s = g_wts[OBC + co];
    #pragma unroll
    for (int f = 0; f < CH; ++f)
      s += __uint_as_float(g_gmax[g*CH + f]) * g_wts[OWC + f*NCLS + co];
    out[g*NCLS + co] = s;                     // float32 out (reference dtype)
  }
}

extern "C" void kernel_launch(void* const* d_in, const int* in_sizes, int n_in,
                              void* d_out, int out_size, void* d_ws, size_t ws_size,
                              hipStream_t stream) {
  const void* pos = d_in[0];
  const void* nrm = d_in[1];
  // d_in[2] = batch (int32) -- unused, batches are uniform
  const void* w1a = d_in[3];
  const void* b1a = d_in[4];
  const void* w1b = d_in[5];
  const void* b1b = d_in[6];
  const void* w2a = d_in[7];
  const void* b2a = d_in[8];
  const void* w2b = d_in[9];
  const void* b2b = d_in[10];
  const void* wc  = d_in[11];
  const void* bc  = d_in[12];

  wprep_kernel<<<1,      256, 0, stream>>>(nrm, w1a, b1a, w1b, b1b, w2a, b2a, w2b, b2b, wc, bc);
  prep_kernel <<<MM/256, 256, 0, stream>>>(pos, nrm);
  knn_kernel  <<<MM/4,   256, 0, stream>>>();
  conv1_kernel<<<MM/8,   256, 0, stream>>>();
  conv2_kernel<<<MM/8,   256, 0, stream>>>();
  pmax_kernel <<<NB*32,  256, 0, stream>>>();
  head_kernel <<<NB,     64,  0, stream>>>((float*)d_out);
}

// Round 12
// 332.957 us; speedup vs baseline: 1.3843x; 1.0320x over previous
//
#include <hip/hip_runtime.h>
#include <hip/hip_bf16.h>
#include <math.h>

#define NB 8
#define NN 4096
#define KK 16
#define MM (NB*NN)
#define CH 32
#define SLOTS 17
#define NCLS 40
#define BIG 3.0e38f
#define CAP 96    // survivors ~18-25 with extraction threshold; P(>96) ~ 1e-12

// Weight table offsets (floats)
#define OW1A 0
#define OB1A 128
#define OW1B 160
#define OB1B 1184
#define OW2A 1216
#define OB2A 2368
#define OW2B 2400
#define OB2B 3424
#define OWC  3456
#define OBC  4736
#define NWTS 4776

// Module-global scratch (~11 MB): no assumptions about ws_size.
__device__ float4 g_pos4[MM];
__device__ float4 g_nrm4[MM];
__device__ int    g_nbr[MM*KK];
__device__ float  g_u[MM*CH];
__device__ float  g_x2[MM*CH];
__device__ float  g_wts[NWTS];
__device__ unsigned int g_gmax[NB*CH];
__device__ int    g_isf32;

__device__ __forceinline__ float bf(const __hip_bfloat16 x) { return __bfloat162float(x); }

__device__ __forceinline__ float ldf(const void* p, int i, bool f32) {
  return f32 ? ((const float*)p)[i] : bf(((const __hip_bfloat16*)p)[i]);
}

__device__ __forceinline__ float angf(float ax, float ay, float az,
                                      float bx, float by, float bz) {
  float cx = ay*bz - az*by;
  float cy = az*bx - ax*bz;
  float cz = ax*by - ay*bx;
  float s  = cx*cx + cy*cy + cz*cz;
  float cn = s > 0.f ? sqrtf(s) : 0.f;
  float d  = ax*bx + ay*by + az*bz;
  return (cn > 0.f || d != 0.f) ? atan2f(cn, d) : 0.f;
}

__device__ __forceinline__ void ppf4(const float4 pi, const float4 ni,
                                     const float4 pj, const float4 nj, float* f) {
  float px = pj.x - pi.x, py = pj.y - pi.y, pz = pj.z - pi.z;
  float s = px*px + py*py + pz*pz;
  f[0] = s > 0.f ? sqrtf(s) : 0.f;
  f[1] = angf(ni.x, ni.y, ni.z, px, py, pz);
  f[2] = angf(nj.x, nj.y, nj.z, px, py, pz);
  f[3] = angf(ni.x, ni.y, ni.z, nj.x, nj.y, nj.z);
}

// ---------------- wprep: parallel dtype vote + weights->fp32 + zero g_gmax ----------------
__global__ __launch_bounds__(256) void wprep_kernel(
    const void* nrm, const void* w1a, const void* b1a, const void* w1b,
    const void* b1b, const void* w2a, const void* b2a, const void* w2b,
    const void* b2b, const void* wc, const void* bc) {
  __shared__ int sflag;
  const int tid = threadIdx.x;
  if (tid < 64) {
    const float* nf = (const float*)nrm;
    const __hip_bfloat16* nh = (const __hip_bfloat16*)nrm;
    float x = nf[3*tid], y = nf[3*tid+1], z = nf[3*tid+2];
    float ss = x*x + y*y + z*z;
    bool okf = (ss > 0.98f && ss < 1.02f);
    float a = bf(nh[3*tid]), b2 = bf(nh[3*tid+1]), c2 = bf(nh[3*tid+2]);
    float sb = a*a + b2*b2 + c2*c2;
    bool okb = (sb > 0.95f && sb < 1.05f);
    unsigned long long mf = __ballot(okf), mb = __ballot(okb);
    if (tid == 0) {
      sflag = (__popcll(mf) >= __popcll(mb)) ? 1 : 0;
      g_isf32 = sflag;
    }
  }
  __syncthreads();
  const bool f32 = sflag != 0;
  for (int i = tid; i < NB*CH; i += 256) g_gmax[i] = 0u;   // max accumulator (x2 >= 0)
  for (int i = tid; i < 128;  i += 256) g_wts[OW1A + i] = ldf(w1a, i, f32);
  for (int i = tid; i < 32;   i += 256) g_wts[OB1A + i] = ldf(b1a, i, f32);
  for (int i = tid; i < 1024; i += 256) g_wts[OW1B + i] = ldf(w1b, i, f32);
  for (int i = tid; i < 32;   i += 256) g_wts[OB1B + i] = ldf(b1b, i, f32);
  for (int i = tid; i < 1152; i += 256) g_wts[OW2A + i] = ldf(w2a, i, f32);
  for (int i = tid; i < 32;   i += 256) g_wts[OB2A + i] = ldf(b2a, i, f32);
  for (int i = tid; i < 1024; i += 256) g_wts[OW2B + i] = ldf(w2b, i, f32);
  for (int i = tid; i < 32;   i += 256) g_wts[OB2B + i] = ldf(b2b, i, f32);
  for (int i = tid; i < 1280; i += 256) g_wts[OWC  + i] = ldf(wc,  i, f32);
  for (int i = tid; i < 40;   i += 256) g_wts[OBC  + i] = ldf(bc,  i, f32);
}

// ---------------- prep: inputs -> float4 (pos.w = |p|^2 f32, filter only) ----------------
__global__ __launch_bounds__(256) void prep_kernel(const void* __restrict__ pos,
                                                   const void* __restrict__ nrm) {
  const bool f32 = g_isf32 != 0;
  int i = blockIdx.x*256 + threadIdx.x;
  float x = ldf(pos, 3*i, f32), y = ldf(pos, 3*i+1, f32), z = ldf(pos, 3*i+2, f32);
  float sq = x*x + y*y + z*z;
  g_pos4[i] = make_float4(x, y, z, sq);
  float a = ldf(nrm, 3*i, f32), b = ldf(nrm, 3*i+1, f32), c = ldf(nrm, 3*i+2, f32);
  g_nrm4[i] = make_float4(a, b, c, 0.f);
}

// ---------------- kNN: whole-batch LDS tile, 4 queries/wave, 1 barrier total --------------
// Filter metric d2' = o.w - 2*dot(q,o) (me.w dropped: constant shift per query,
// ranking-invariant). Pass 1: per-LANE min over its 64-candidate column (4 queries
// in parallel per ds_read). Threshold: 16 rounds of wave-min-extract-and-mask =>
// >=16 distinct candidates <= T (each extracted lane contributes >=1); survivors
// ~18-25 (coupon collector over 64 lanes). Tf = T + margin >> f32 error => every
// f64-top-16 candidate provably survives. Pass 2: recompute, sparse per-query
// collect (wave-private lists). Then f64 rescore from the LDS tile (numpy-exact
// association) + exact lexicographic (d2_f64, idx) rank. No per-thread arrays
// (no spill); all post-staging LDS is read-only tile or wave-private.
__global__ __launch_bounds__(256) void knn_kernel() {
  __shared__ float4 tile[NN];          // 65536 B: whole batch
  __shared__ int    ilst[16][CAP];     //  6144 B
  __shared__ double dlst[4][CAP];      //  3072 B
  __shared__ int    cnt[16];
  const int tid  = threadIdx.x;
  const int w    = tid >> 6, lane = tid & 63;
  const int blk  = blockIdx.x;
  const int b    = blk >> 8;                   // 256 blocks per batch
  const int qb   = ((blk & 255) << 4) | (w << 2); // first of this wave's 4 queries
  const float4* bp = g_pos4 + b*NN;

  #pragma unroll
  for (int k = 0; k < 16; ++k) tile[k*256 + tid] = bp[k*256 + tid];
  __syncthreads();                             // the only barrier

  const float4 q0 = tile[qb], q1 = tile[qb+1], q2 = tile[qb+2], q3 = tile[qb+3];

  // ---- pass 1: per-lane column mins for 4 queries ----
  float m0 = BIG, m1 = BIG, m2 = BIG, m3 = BIG;
  #pragma unroll 4
  for (int it = 0; it < 64; ++it) {
    int cand = it*64 + lane;
    float4 o = tile[cand];
    float d0 = __builtin_fmaf(-2.f, q0.x*o.x + q0.y*o.y + q0.z*o.z, o.w);
    float d1 = __builtin_fmaf(-2.f, q1.x*o.x + q1.y*o.y + q1.z*o.z, o.w);
    float d2 = __builtin_fmaf(-2.f, q2.x*o.x + q2.y*o.y + q2.z*o.z, o.w);
    float d3 = __builtin_fmaf(-2.f, q3.x*o.x + q3.y*o.y + q3.z*o.z, o.w);
    if (cand == qb  ) d0 = BIG;
    if (cand == qb+1) d1 = BIG;
    if (cand == qb+2) d2 = BIG;
    if (cand == qb+3) d3 = BIG;
    m0 = fminf(m0, d0); m1 = fminf(m1, d1); m2 = fminf(m2, d2); m3 = fminf(m3, d3);
  }

  // ---- threshold: 16 wave-min extraction rounds per query ----
  float Tf[4];
  {
    float mm[4] = {m0, m1, m2, m3};
    #pragma unroll
    for (int qq = 0; qq < 4; ++qq) {
      float v = mm[qq], T = 0.f;
      for (int k = 0; k < 16; ++k) {
        float mn = v;
        #pragma unroll
        for (int d = 1; d < 64; d <<= 1) mn = fminf(mn, __shfl_xor(mn, d));
        T = mn;
        v = (v == mn) ? BIG : v;               // mask out extracted lane(s)
      }
      Tf[qq] = T + 2e-5f + 1e-5f*fabsf(T);     // margin >> f32 d2' error
    }
  }

  if (lane < 4) cnt[(w<<2) | lane] = 0;        // wave-private counters

  // ---- pass 2: recompute + sparse collect into wave-private lists ----
  #pragma unroll 4
  for (int it = 0; it < 64; ++it) {
    int cand = it*64 + lane;
    float4 o = tile[cand];
    float d0 = __builtin_fmaf(-2.f, q0.x*o.x + q0.y*o.y + q0.z*o.z, o.w);
    float d1 = __builtin_fmaf(-2.f, q1.x*o.x + q1.y*o.y + q1.z*o.z, o.w);
    float d2 = __builtin_fmaf(-2.f, q2.x*o.x + q2.y*o.y + q2.z*o.z, o.w);
    float d3 = __builtin_fmaf(-2.f, q3.x*o.x + q3.y*o.y + q3.z*o.z, o.w);
    if (d0 <= Tf[0] && cand != qb) {
      int p = atomicAdd(&cnt[(w<<2)|0], 1);
      if (p < CAP) ilst[(w<<2)|0][p] = cand;
    }
    if (d1 <= Tf[1] && cand != qb+1) {
      int p = atomicAdd(&cnt[(w<<2)|1], 1);
      if (p < CAP) ilst[(w<<2)|1][p] = cand;
    }
    if (d2 <= Tf[2] && cand != qb+2) {
      int p = atomicAdd(&cnt[(w<<2)|2], 1);
      if (p < CAP) ilst[(w<<2)|2][p] = cand;
    }
    if (d3 <= Tf[3] && cand != qb+3) {
      int p = atomicAdd(&cnt[(w<<2)|3], 1);
      if (p < CAP) ilst[(w<<2)|3][p] = cand;
    }
  }

  // ---- per query: f64 rescore (numpy-exact, from LDS tile) + exact rank ----
  #pragma unroll 1
  for (int qq = 0; qq < 4; ++qq) {
    const int qi = qb + qq;
    const int m = min(cnt[(w<<2)|qq], CAP);
    const float4 q = tile[qi];
    const double mx = (double)q.x, my_ = (double)q.y, mz = (double)q.z;
    const double sqme = (mx*mx + my_*my_) + mz*mz;
    if (lane < m) {                            // m <= CAP=96 needs 2 chunks max
      for (int e = lane; e < m; e += 64) {
        int ci = ilst[(w<<2)|qq][e];
        float4 o = tile[ci];
        double ox = (double)o.x, oy = (double)o.y, oz = (double)o.z;
        double sqo = (ox*ox + oy*oy) + oz*oz;
        double dt  = (mx*ox + my_*oy) + mz*oz;
        dlst[w][e] = (sqme + sqo) - 2.0*dt;
      }
    }
    for (int e = lane; e < m; e += 64) {
      double myd = dlst[w][e];
      int myi = ilst[(w<<2)|qq][e];
      int rank = 0;
      for (int o = 0; o < m; ++o) {            // broadcast LDS reads
        double od = dlst[w][o];
        int oi = ilst[(w<<2)|qq][o];
        rank += (od < myd) || (od == myd && oi < myi);
      }
      if (rank < KK) g_nbr[(b*NN + qi)*KK + rank] = b*NN + myi;
    }
  }
}

// ---------------- conv1: 8 nodes/block, fused u = relu(max(msg1)) @ w2a[0:32] ----------------
__global__ __launch_bounds__(256) void conv1_kernel() {
  __shared__ __align__(16) float fe[136][4];
  __shared__ __align__(16) float h1s[8*SLOTS*CH];
  __shared__ __align__(16) float xs[8][CH];
  const int tid = threadIdx.x;
  const int c = tid & 31;
  const int node0 = blockIdx.x << 3;
  float w1a_c[4], w1b_c[32], w2a_c[32];
  #pragma unroll
  for (int f = 0; f < 4; ++f)  w1a_c[f] = g_wts[OW1A + f*CH + c];
  #pragma unroll
  for (int k = 0; k < 32; ++k) w1b_c[k] = g_wts[OW1B + k*CH + c];
  #pragma unroll
  for (int k = 0; k < 32; ++k) w2a_c[k] = g_wts[OW2A + k*CH + c];
  const float b1a_c = g_wts[OB1A + c], b1b_c = g_wts[OB1B + c];

  if (tid < 136) {
    int ns = tid / 17, slot = tid - ns*17;
    int i = node0 + ns;
    int j = (slot < KK) ? g_nbr[i*KK + slot] : i;   // slot 16 = self-loop
    ppf4(g_pos4[i], g_nrm4[i], g_pos4[j], g_nrm4[j], fe[tid]);
  }
  __syncthreads();
  #pragma unroll
  for (int it = 0; it < 17; ++it) {
    int idx = it*256 + tid;                   // (e, c) with c == tid&31
    int e = idx >> 5;
    float4 f4 = *(const float4*)fe[e];
    float h = b1a_c + f4.x*w1a_c[0] + f4.y*w1a_c[1] + f4.z*w1a_c[2] + f4.w*w1a_c[3];
    h1s[idx] = fmaxf(h, 0.f);
  }
  __syncthreads();
  const int ns = tid >> 5;
  const int i  = node0 + ns;
  float acc = -BIG;
  #pragma unroll
  for (int slot = 0; slot < SLOTS; ++slot) {
    const float* hr = &h1s[(ns*SLOTS + slot)*CH];
    float msg = b1b_c;
    #pragma unroll
    for (int k4 = 0; k4 < 8; ++k4) {
      float4 h4 = *(const float4*)(hr + 4*k4);
      msg += h4.x*w1b_c[4*k4] + h4.y*w1b_c[4*k4+1] + h4.z*w1b_c[4*k4+2] + h4.w*w1b_c[4*k4+3];
    }
    acc = fmaxf(acc, msg);
  }
  xs[ns][c] = fmaxf(acc, 0.f);                // x1 = relu(segment_max)
  __syncthreads();
  float uu = 0.f;
  #pragma unroll
  for (int k4 = 0; k4 < 8; ++k4) {
    float4 x4 = *(const float4*)&xs[ns][4*k4];
    uu += x4.x*w2a_c[4*k4] + x4.y*w2a_c[4*k4+1] + x4.z*w2a_c[4*k4+2] + x4.w*w2a_c[4*k4+3];
  }
  g_u[i*CH + c] = uu;                         // u = x1 @ w2a[0:32,:]
}

// ---------------- conv2 ----------------
__global__ __launch_bounds__(256) void conv2_kernel() {
  __shared__ __align__(16) float fe[136][4];
  __shared__ int jn[136];
  __shared__ __align__(16) float h2s[8*SLOTS*CH];
  const int tid = threadIdx.x;
  const int c = tid & 31;
  const int node0 = blockIdx.x << 3;
  float w2aL_c[4], w2b_c[32];
  #pragma unroll
  for (int f = 0; f < 4; ++f)  w2aL_c[f] = g_wts[OW2A + (CH + f)*CH + c];
  #pragma unroll
  for (int k = 0; k < 32; ++k) w2b_c[k] = g_wts[OW2B + k*CH + c];
  const float b2a_c = g_wts[OB2A + c], b2b_c = g_wts[OB2B + c];

  if (tid < 136) {
    int ns = tid / 17, slot = tid - ns*17;
    int i = node0 + ns;
    int j = (slot < KK) ? g_nbr[i*KK + slot] : i;
    jn[tid] = j;
    ppf4(g_pos4[i], g_nrm4[i], g_pos4[j], g_nrm4[j], fe[tid]);
  }
  __syncthreads();
  #pragma unroll
  for (int it = 0; it < 17; ++it) {
    int idx = it*256 + tid;
    int e = idx >> 5;
    float4 f4 = *(const float4*)fe[e];
    float uv = g_u[jn[e]*CH + c];             // x_j @ w2a[0:32] precomputed
    float h = b2a_c + uv + f4.x*w2aL_c[0] + f4.y*w2aL_c[1] + f4.z*w2aL_c[2] + f4.w*w2aL_c[3];
    h2s[idx] = fmaxf(h, 0.f);
  }
  __syncthreads();
  const int ns = tid >> 5;
  float acc = -BIG;
  #pragma unroll
  for (int slot = 0; slot < SLOTS; ++slot) {
    const float* hr = &h2s[(ns*SLOTS + slot)*CH];
    float msg = b2b_c;
    #pragma unroll
    for (int k4 = 0; k4 < 8; ++k4) {
      float4 h4 = *(const float4*)(hr + 4*k4);
      msg += h4.x*w2b_c[4*k4] + h4.y*w2b_c[4*k4+1] + h4.z*w2b_c[4*k4+2] + h4.w*w2b_c[4*k4+3];
    }
    acc = fmaxf(acc, msg);
  }
  g_x2[(node0 + ns)*CH + c] = fmaxf(acc, 0.f);
}

// ---------------- pmax: 256 blocks, coalesced partial max + device atomicMax ----------------
__global__ __launch_bounds__(256) void pmax_kernel() {
  __shared__ float red[8][CH];
  const int g = blockIdx.x >> 5;              // graph
  const int chunk = blockIdx.x & 31;          // 128 nodes per block
  const int c = threadIdx.x & 31, sub = threadIdx.x >> 5;
  const float* base = g_x2 + (size_t)(g*NN + chunk*128)*CH;
  float mx = 0.f;                             // x2 >= 0 (relu)
  #pragma unroll
  for (int n = 0; n < 16; ++n)
    mx = fmaxf(mx, base[(n*8 + sub)*CH + c]);
  red[sub][c] = mx;
  __syncthreads();
  if (threadIdx.x < CH) {
    float m2 = red[0][c];
    #pragma unroll
    for (int r = 1; r < 8; ++r) m2 = fmaxf(m2, red[r][c]);
    atomicMax(&g_gmax[g*CH + c], __float_as_uint(m2));  // exact for floats >= 0
  }
}

// ---------------- head (float32 output) ----------------
__global__ __launch_bounds__(64) void head_kernel(float* __restrict__ out) {
  const int g = blockIdx.x;
  const int co = threadIdx.x;
  if (co < NCLS) {
    float s = g_wts[OBC + co];
    #pragma unroll
    for (int f = 0; f < CH; ++f)
      s += __uint_as_float(g_gmax[g*CH + f]) * g_wts[OWC + f*NCLS + co];
    out[g*NCLS + co] = s;                     // float32 out (reference dtype)
  }
}

extern "C" void kernel_launch(void* const* d_in, const int* in_sizes, int n_in,
                              void* d_out, int out_size, void* d_ws, size_t ws_size,
                              hipStream_t stream) {
  const void* pos = d_in[0];
  const void* nrm = d_in[1];
  // d_in[2] = batch (int32) -- unused, batches are uniform
  const void* w1a = d_in[3];
  const void* b1a = d_in[4];
  const void* w1b = d_in[5];
  const void* b1b = d_in[6];
  const void* w2a = d_in[7];
  const void* b2a = d_in[8];
  const void* w2b = d_in[9];
  const void* b2b = d_in[10];
  const void* wc  = d_in[11];
  const void* bc  = d_in[12];

  wprep_kernel<<<1,      256, 0, stream>>>(nrm, w1a, b1a, w1b, b1b, w2a, b2a, w2b, b2b, wc, bc);
  prep_kernel <<<MM/256, 256, 0, stream>>>(pos, nrm);
  knn_kernel  <<<MM/16,  256, 0, stream>>>();
  conv1_kernel<<<MM/8,   256, 0, stream>>>();
  conv2_kernel<<<MM/8,   256, 0, stream>>>();
  pmax_kernel <<<NB*32,  256, 0, stream>>>();
  head_kernel <<<NB,     64,  0, stream>>>((float*)d_out);
}

// Round 13
// 317.617 us; speedup vs baseline: 1.4511x; 1.0483x over previous
//
#include <hip/hip_runtime.h>
#include <hip/hip_bf16.h>
#include <math.h>

#define NB 8
#define NN 4096
#define KK 16
#define MM (NB*NN)
#define CH 32
#define SLOTS 17
#define NCLS 40
#define BIG 3.0e38f
#define CAP 96    // survivors ~20 with extraction threshold (validated R12 x2)

// Weight table offsets (floats)
#define OW1A 0
#define OB1A 128
#define OW1B 160
#define OB1B 1184
#define OW2A 1216
#define OB2A 2368
#define OW2B 2400
#define OB2B 3424
#define OWC  3456
#define OBC  4736
#define NWTS 4776

// Module-global scratch (~11 MB): no assumptions about ws_size.
__device__ float4 g_pos4[MM];
__device__ float4 g_nrm4[MM];
__device__ int    g_nbr[MM*KK];
__device__ float  g_u[MM*CH];
__device__ float  g_x2[MM*CH];
__device__ float  g_wts[NWTS];
__device__ unsigned int g_gmax[NB*CH];
__device__ int    g_isf32;

__device__ __forceinline__ float bf(const __hip_bfloat16 x) { return __bfloat162float(x); }

__device__ __forceinline__ float ldf(const void* p, int i, bool f32) {
  return f32 ? ((const float*)p)[i] : bf(((const __hip_bfloat16*)p)[i]);
}

__device__ __forceinline__ float angf(float ax, float ay, float az,
                                      float bx, float by, float bz) {
  float cx = ay*bz - az*by;
  float cy = az*bx - ax*bz;
  float cz = ax*by - ay*bx;
  float s  = cx*cx + cy*cy + cz*cz;
  float cn = s > 0.f ? sqrtf(s) : 0.f;
  float d  = ax*bx + ay*by + az*bz;
  return (cn > 0.f || d != 0.f) ? atan2f(cn, d) : 0.f;
}

__device__ __forceinline__ void ppf4(const float4 pi, const float4 ni,
                                     const float4 pj, const float4 nj, float* f) {
  float px = pj.x - pi.x, py = pj.y - pi.y, pz = pj.z - pi.z;
  float s = px*px + py*py + pz*pz;
  f[0] = s > 0.f ? sqrtf(s) : 0.f;
  f[1] = angf(ni.x, ni.y, ni.z, px, py, pz);
  f[2] = angf(nj.x, nj.y, nj.z, px, py, pz);
  f[3] = angf(ni.x, ni.y, ni.z, nj.x, nj.y, nj.z);
}

// ---------------- wprep: parallel dtype vote + weights->fp32 + zero g_gmax ----------------
__global__ __launch_bounds__(256) void wprep_kernel(
    const void* nrm, const void* w1a, const void* b1a, const void* w1b,
    const void* b1b, const void* w2a, const void* b2a, const void* w2b,
    const void* b2b, const void* wc, const void* bc) {
  __shared__ int sflag;
  const int tid = threadIdx.x;
  if (tid < 64) {
    const float* nf = (const float*)nrm;
    const __hip_bfloat16* nh = (const __hip_bfloat16*)nrm;
    float x = nf[3*tid], y = nf[3*tid+1], z = nf[3*tid+2];
    float ss = x*x + y*y + z*z;
    bool okf = (ss > 0.98f && ss < 1.02f);
    float a = bf(nh[3*tid]), b2 = bf(nh[3*tid+1]), c2 = bf(nh[3*tid+2]);
    float sb = a*a + b2*b2 + c2*c2;
    bool okb = (sb > 0.95f && sb < 1.05f);
    unsigned long long mf = __ballot(okf), mb = __ballot(okb);
    if (tid == 0) {
      sflag = (__popcll(mf) >= __popcll(mb)) ? 1 : 0;
      g_isf32 = sflag;
    }
  }
  __syncthreads();
  const bool f32 = sflag != 0;
  for (int i = tid; i < NB*CH; i += 256) g_gmax[i] = 0u;   // max accumulator (x2 >= 0)
  for (int i = tid; i < 128;  i += 256) g_wts[OW1A + i] = ldf(w1a, i, f32);
  for (int i = tid; i < 32;   i += 256) g_wts[OB1A + i] = ldf(b1a, i, f32);
  for (int i = tid; i < 1024; i += 256) g_wts[OW1B + i] = ldf(w1b, i, f32);
  for (int i = tid; i < 32;   i += 256) g_wts[OB1B + i] = ldf(b1b, i, f32);
  for (int i = tid; i < 1152; i += 256) g_wts[OW2A + i] = ldf(w2a, i, f32);
  for (int i = tid; i < 32;   i += 256) g_wts[OB2A + i] = ldf(b2a, i, f32);
  for (int i = tid; i < 1024; i += 256) g_wts[OW2B + i] = ldf(w2b, i, f32);
  for (int i = tid; i < 32;   i += 256) g_wts[OB2B + i] = ldf(b2b, i, f32);
  for (int i = tid; i < 1280; i += 256) g_wts[OWC  + i] = ldf(wc,  i, f32);
  for (int i = tid; i < 40;   i += 256) g_wts[OBC  + i] = ldf(bc,  i, f32);
}

// ---------------- prep: inputs -> float4 (pos.w = |p|^2 f32, filter only) ----------------
__global__ __launch_bounds__(256) void prep_kernel(const void* __restrict__ pos,
                                                   const void* __restrict__ nrm) {
  const bool f32 = g_isf32 != 0;
  int i = blockIdx.x*256 + threadIdx.x;
  float x = ldf(pos, 3*i, f32), y = ldf(pos, 3*i+1, f32), z = ldf(pos, 3*i+2, f32);
  float sq = x*x + y*y + z*z;
  g_pos4[i] = make_float4(x, y, z, sq);
  float a = ldf(nrm, 3*i, f32), b = ldf(nrm, 3*i+1, f32), c = ldf(nrm, 3*i+2, f32);
  g_nrm4[i] = make_float4(a, b, c, 0.f);
}

// ---------------- kNN: SoA whole-batch tile, 8 queries/wave, 1 barrier ------------------
// Filter metric d2' = o.w - 2*dot(q,o) computed as 3 fma with q2 = -2q (filter-only;
// margin 4e-5 abs + 1e-5 rel >> 1.4e-5 worst-case f32 error keeps the f64-top-16
// survival proof). Self is NOT masked in pass 1: self d2' = -|q|^2 is the STRICT
// global min (Cauchy-Schwarz, no duplicate points), so the threshold runs 17
// extraction rounds (round 1 removes self) => >=16 distinct non-self candidates
// <= T. SoA tile (sx/sy/sz/sw): stride-1 ds_read_b32 = 2-way bank aliasing = free,
// vs the float4 b128 pattern's 8-way conflict (R12: 140K conflict cycles).
// Pass 2 recomputes and collects (cand != qi excluded); f64 rescore (numpy-exact
// association, from the tile) + exact lexicographic (d2_f64, idx) rank.
__global__ __launch_bounds__(256) void knn_kernel() {
  __shared__ float sx[NN], sy[NN], sz[NN], sw[NN];  // 65536 B (SoA tile)
  __shared__ int    ilst[32][CAP];                  // 12288 B
  __shared__ double dlst[4][CAP];                   //  3072 B
  __shared__ int    cnt[32];
  const int tid  = threadIdx.x;
  const int w    = tid >> 6, lane = tid & 63;
  const int blk  = blockIdx.x;
  const int b    = blk >> 7;                        // 128 blocks per batch
  const int qbw  = ((blk & 127) << 5) | (w << 3);   // first of this wave's 8 queries
  const float4* bp = g_pos4 + b*NN;

  #pragma unroll
  for (int k = 0; k < 16; ++k) {
    int idx = k*256 + tid;
    float4 o = bp[idx];
    sx[idx] = o.x; sy[idx] = o.y; sz[idx] = o.z; sw[idx] = o.w;
  }
  __syncthreads();                                  // the only barrier

  // queries (broadcast LDS reads), pre-negated x(-2)
  float q2x[8], q2y[8], q2z[8];
  #pragma unroll
  for (int qq = 0; qq < 8; ++qq) {
    int qi = qbw + qq;
    q2x[qq] = -2.f*sx[qi]; q2y[qq] = -2.f*sy[qi]; q2z[qq] = -2.f*sz[qi];
  }

  // ---- pass 1: per-lane column mins for 8 queries (self included) ----
  float mn[8];
  #pragma unroll
  for (int qq = 0; qq < 8; ++qq) mn[qq] = BIG;
  #pragma unroll 4
  for (int it = 0; it < 64; ++it) {
    int idx = it*64 + lane;
    float ox = sx[idx], oy = sy[idx], oz = sz[idx], ow = sw[idx];
    #pragma unroll
    for (int qq = 0; qq < 8; ++qq) {
      float d = __builtin_fmaf(q2x[qq], ox,
                __builtin_fmaf(q2y[qq], oy,
                __builtin_fmaf(q2z[qq], oz, ow)));
      mn[qq] = fminf(mn[qq], d);
    }
  }

  // ---- threshold: 17 extraction rounds (round 1 = self, strict global min) ----
  float Tf[8];
  #pragma unroll
  for (int qq = 0; qq < 8; ++qq) {
    float v = mn[qq], T = 0.f;
    for (int k = 0; k < 17; ++k) {
      float m2 = v;
      #pragma unroll
      for (int d = 1; d < 64; d <<= 1) m2 = fminf(m2, __shfl_xor(m2, d));
      T = m2;
      v = (v == m2) ? BIG : v;                      // remove extracted lane(s)
    }
    Tf[qq] = T + 4e-5f + 1e-5f*fabsf(T);            // margin >> f32 d2' abs error
  }

  if (lane < 8) cnt[(w<<3) | lane] = 0;             // wave-private counters

  // ---- pass 2: recompute + sparse collect into wave-private lists ----
  #pragma unroll 4
  for (int it = 0; it < 64; ++it) {
    int idx = it*64 + lane;
    float ox = sx[idx], oy = sy[idx], oz = sz[idx], ow = sw[idx];
    #pragma unroll
    for (int qq = 0; qq < 8; ++qq) {
      float d = __builtin_fmaf(q2x[qq], ox,
                __builtin_fmaf(q2y[qq], oy,
                __builtin_fmaf(q2z[qq], oz, ow)));
      if (d <= Tf[qq] && idx != qbw + qq) {
        int p = atomicAdd(&cnt[(w<<3)|qq], 1);
        if (p < CAP) ilst[(w<<3)|qq][p] = idx;
      }
    }
  }

  // ---- per query: f64 rescore (numpy-exact, from LDS tile) + exact rank ----
  #pragma unroll 1
  for (int qq = 0; qq < 8; ++qq) {
    const int qi = qbw + qq;
    const int m = min(cnt[(w<<3)|qq], CAP);
    const double mx = (double)sx[qi], my_ = (double)sy[qi], mz = (double)sz[qi];
    const double sqme = (mx*mx + my_*my_) + mz*mz;
    for (int e = lane; e < m; e += 64) {
      int ci = ilst[(w<<3)|qq][e];
      double ox = (double)sx[ci], oy = (double)sy[ci], oz = (double)sz[ci];
      double sqo = (ox*ox + oy*oy) + oz*oz;
      double dt  = (mx*ox + my_*oy) + mz*oz;
      dlst[w][e] = (sqme + sqo) - 2.0*dt;
    }
    for (int e = lane; e < m; e += 64) {
      double myd = dlst[w][e];
      int myi = ilst[(w<<3)|qq][e];
      int rank = 0;
      for (int o = 0; o < m; ++o) {                 // broadcast LDS reads
        double od = dlst[w][o];
        int oi = ilst[(w<<3)|qq][o];
        rank += (od < myd) || (od == myd && oi < myi);
      }
      if (rank < KK) g_nbr[(b*NN + qi)*KK + rank] = b*NN + myi;
    }
  }
}

// ---------------- conv1: 8 nodes/block, fused u = relu(max(msg1)) @ w2a[0:32] ----------------
__global__ __launch_bounds__(256) void conv1_kernel() {
  __shared__ __align__(16) float fe[136][4];
  __shared__ __align__(16) float h1s[8*SLOTS*CH];
  __shared__ __align__(16) float xs[8][CH];
  const int tid = threadIdx.x;
  const int c = tid & 31;
  const int node0 = blockIdx.x << 3;
  float w1a_c[4], w1b_c[32], w2a_c[32];
  #pragma unroll
  for (int f = 0; f < 4; ++f)  w1a_c[f] = g_wts[OW1A + f*CH + c];
  #pragma unroll
  for (int k = 0; k < 32; ++k) w1b_c[k] = g_wts[OW1B + k*CH + c];
  #pragma unroll
  for (int k = 0; k < 32; ++k) w2a_c[k] = g_wts[OW2A + k*CH + c];
  const float b1a_c = g_wts[OB1A + c], b1b_c = g_wts[OB1B + c];

  if (tid < 136) {
    int ns = tid / 17, slot = tid - ns*17;
    int i = node0 + ns;
    int j = (slot < KK) ? g_nbr[i*KK + slot] : i;   // slot 16 = self-loop
    ppf4(g_pos4[i], g_nrm4[i], g_pos4[j], g_nrm4[j], fe[tid]);
  }
  __syncthreads();
  #pragma unroll
  for (int it = 0; it < 17; ++it) {
    int idx = it*256 + tid;                   // (e, c) with c == tid&31
    int e = idx >> 5;
    float4 f4 = *(const float4*)fe[e];
    float h = b1a_c + f4.x*w1a_c[0] + f4.y*w1a_c[1] + f4.z*w1a_c[2] + f4.w*w1a_c[3];
    h1s[idx] = fmaxf(h, 0.f);
  }
  __syncthreads();
  const int ns = tid >> 5;
  const int i  = node0 + ns;
  float acc = -BIG;
  #pragma unroll
  for (int slot = 0; slot < SLOTS; ++slot) {
    const float* hr = &h1s[(ns*SLOTS + slot)*CH];
    float msg = b1b_c;
    #pragma unroll
    for (int k4 = 0; k4 < 8; ++k4) {
      float4 h4 = *(const float4*)(hr + 4*k4);
      msg += h4.x*w1b_c[4*k4] + h4.y*w1b_c[4*k4+1] + h4.z*w1b_c[4*k4+2] + h4.w*w1b_c[4*k4+3];
    }
    acc = fmaxf(acc, msg);
  }
  xs[ns][c] = fmaxf(acc, 0.f);                // x1 = relu(segment_max)
  __syncthreads();
  float uu = 0.f;
  #pragma unroll
  for (int k4 = 0; k4 < 8; ++k4) {
    float4 x4 = *(const float4*)&xs[ns][4*k4];
    uu += x4.x*w2a_c[4*k4] + x4.y*w2a_c[4*k4+1] + x4.z*w2a_c[4*k4+2] + x4.w*w2a_c[4*k4+3];
  }
  g_u[i*CH + c] = uu;                         // u = x1 @ w2a[0:32,:]
}

// ---------------- conv2 ----------------
__global__ __launch_bounds__(256) void conv2_kernel() {
  __shared__ __align__(16) float fe[136][4];
  __shared__ int jn[136];
  __shared__ __align__(16) float h2s[8*SLOTS*CH];
  const int tid = threadIdx.x;
  const int c = tid & 31;
  const int node0 = blockIdx.x << 3;
  float w2aL_c[4], w2b_c[32];
  #pragma unroll
  for (int f = 0; f < 4; ++f)  w2aL_c[f] = g_wts[OW2A + (CH + f)*CH + c];
  #pragma unroll
  for (int k = 0; k < 32; ++k) w2b_c[k] = g_wts[OW2B + k*CH + c];
  const float b2a_c = g_wts[OB2A + c], b2b_c = g_wts[OB2B + c];

  if (tid < 136) {
    int ns = tid / 17, slot = tid - ns*17;
    int i = node0 + ns;
    int j = (slot < KK) ? g_nbr[i*KK + slot] : i;
    jn[tid] = j;
    ppf4(g_pos4[i], g_nrm4[i], g_pos4[j], g_nrm4[j], fe[tid]);
  }
  __syncthreads();
  #pragma unroll
  for (int it = 0; it < 17; ++it) {
    int idx = it*256 + tid;
    int e = idx >> 5;
    float4 f4 = *(const float4*)fe[e];
    float uv = g_u[jn[e]*CH + c];             // x_j @ w2a[0:32] precomputed
    float h = b2a_c + uv + f4.x*w2aL_c[0] + f4.y*w2aL_c[1] + f4.z*w2aL_c[2] + f4.w*w2aL_c[3];
    h2s[idx] = fmaxf(h, 0.f);
  }
  __syncthreads();
  const int ns = tid >> 5;
  float acc = -BIG;
  #pragma unroll
  for (int slot = 0; slot < SLOTS; ++slot) {
    const float* hr = &h2s[(ns*SLOTS + slot)*CH];
    float msg = b2b_c;
    #pragma unroll
    for (int k4 = 0; k4 < 8; ++k4) {
      float4 h4 = *(const float4*)(hr + 4*k4);
      msg += h4.x*w2b_c[4*k4] + h4.y*w2b_c[4*k4+1] + h4.z*w2b_c[4*k4+2] + h4.w*w2b_c[4*k4+3];
    }
    acc = fmaxf(acc, msg);
  }
  g_x2[(node0 + ns)*CH + c] = fmaxf(acc, 0.f);
}

// ---------------- pmax: 256 blocks, coalesced partial max + device atomicMax ----------------
__global__ __launch_bounds__(256) void pmax_kernel() {
  __shared__ float red[8][CH];
  const int g = blockIdx.x >> 5;              // graph
  const int chunk = blockIdx.x & 31;          // 128 nodes per block
  const int c = threadIdx.x & 31, sub = threadIdx.x >> 5;
  const float* base = g_x2 + (size_t)(g*NN + chunk*128)*CH;
  float mx = 0.f;                             // x2 >= 0 (relu)
  #pragma unroll
  for (int n = 0; n < 16; ++n)
    mx = fmaxf(mx, base[(n*8 + sub)*CH + c]);
  red[sub][c] = mx;
  __syncthreads();
  if (threadIdx.x < CH) {
    float m2 = red[0][c];
    #pragma unroll
    for (int r = 1; r < 8; ++r) m2 = fmaxf(m2, red[r][c]);
    atomicMax(&g_gmax[g*CH + c], __float_as_uint(m2));  // exact for floats >= 0
  }
}

// ---------------- head (float32 output) ----------------
__global__ __launch_bounds__(64) void head_kernel(float* __restrict__ out) {
  const int g = blockIdx.x;
  const int co = threadIdx.x;
  if (co < NCLS) {
    float s = g_wts[OBC + co];
    #pragma unroll
    for (int f = 0; f < CH; ++f)
      s += __uint_as_float(g_gmax[g*CH + f]) * g_wts[OWC + f*NCLS + co];
    out[g*NCLS + co] = s;                     // float32 out (reference dtype)
  }
}

extern "C" void kernel_launch(void* const* d_in, const int* in_sizes, int n_in,
                              void* d_out, int out_size, void* d_ws, size_t ws_size,
                              hipStream_t stream) {
  const void* pos = d_in[0];
  const void* nrm = d_in[1];
  // d_in[2] = batch (int32) -- unused, batches are uniform
  const void* w1a = d_in[3];
  const void* b1a = d_in[4];
  const void* w1b = d_in[5];
  const void* b1b = d_in[6];
  const void* w2a = d_in[7];
  const void* b2a = d_in[8];
  const void* w2b = d_in[9];
  const void* b2b = d_in[10];
  const void* wc  = d_in[11];
  const void* bc  = d_in[12];

  wprep_kernel<<<1,      256, 0, stream>>>(nrm, w1a, b1a, w1b, b1b, w2a, b2a, w2b, b2b, wc, bc);
  prep_kernel <<<MM/256, 256, 0, stream>>>(pos, nrm);
  knn_kernel  <<<MM/32,  256, 0, stream>>>();
  conv1_kernel<<<MM/8,   256, 0, stream>>>();
  conv2_kernel<<<MM/8,   256, 0, stream>>>();
  pmax_kernel <<<NB*32,  256, 0, stream>>>();
  head_kernel <<<NB,     64,  0, stream>>>((float*)d_out);
}

// Round 14
// 282.823 us; speedup vs baseline: 1.6297x; 1.1230x over previous
//
#include <hip/hip_runtime.h>
#include <hip/hip_bf16.h>
#include <math.h>

#define NB 8
#define NN 4096
#define KK 16
#define MM (NB*NN)
#define CH 32
#define SLOTS 17
#define NCLS 40
#define BIG 3.0e38f
#define CAP 96    // survivors ~20-25 with 17th-lane-min threshold (validated R12/R13)

// Weight table offsets (floats)
#define OW1A 0
#define OB1A 128
#define OW1B 160
#define OB1B 1184
#define OW2A 1216
#define OB2A 2368
#define OW2B 2400
#define OB2B 3424
#define OWC  3456
#define OBC  4736
#define NWTS 4776

// Module-global scratch (~11 MB): no assumptions about ws_size.
__device__ float4 g_pos4[MM];
__device__ float4 g_nrm4[MM];
__device__ int    g_nbr[MM*KK];
__device__ float  g_u[MM*CH];
__device__ float  g_x2[MM*CH];
__device__ float  g_wts[NWTS];
__device__ unsigned int g_gmax[NB*CH];
__device__ int    g_isf32;

__device__ __forceinline__ float bf(const __hip_bfloat16 x) { return __bfloat162float(x); }

__device__ __forceinline__ float ldf(const void* p, int i, bool f32) {
  return f32 ? ((const float*)p)[i] : bf(((const __hip_bfloat16*)p)[i]);
}

__device__ __forceinline__ float angf(float ax, float ay, float az,
                                      float bx, float by, float bz) {
  float cx = ay*bz - az*by;
  float cy = az*bx - ax*bz;
  float cz = ax*by - ay*bx;
  float s  = cx*cx + cy*cy + cz*cz;
  float cn = s > 0.f ? sqrtf(s) : 0.f;
  float d  = ax*bx + ay*by + az*bz;
  return (cn > 0.f || d != 0.f) ? atan2f(cn, d) : 0.f;
}

__device__ __forceinline__ void ppf4(const float4 pi, const float4 ni,
                                     const float4 pj, const float4 nj, float* f) {
  float px = pj.x - pi.x, py = pj.y - pi.y, pz = pj.z - pi.z;
  float s = px*px + py*py + pz*pz;
  f[0] = s > 0.f ? sqrtf(s) : 0.f;
  f[1] = angf(ni.x, ni.y, ni.z, px, py, pz);
  f[2] = angf(nj.x, nj.y, nj.z, px, py, pz);
  f[3] = angf(ni.x, ni.y, ni.z, nj.x, nj.y, nj.z);
}

// monotone f32 -> u32 key (order-preserving for all finite floats)
__device__ __forceinline__ unsigned int fkey(float f) {
  unsigned int u = __float_as_uint(f);
  return (u & 0x80000000u) ? ~u : (u | 0x80000000u);
}
__device__ __forceinline__ float funkey(unsigned int k) {
  unsigned int u = (k & 0x80000000u) ? (k ^ 0x80000000u) : ~k;
  return __uint_as_float(u);
}

// ---------------- wprep: parallel dtype vote + weights->fp32 + zero g_gmax ----------------
__global__ __launch_bounds__(256) void wprep_kernel(
    const void* nrm, const void* w1a, const void* b1a, const void* w1b,
    const void* b1b, const void* w2a, const void* b2a, const void* w2b,
    const void* b2b, const void* wc, const void* bc) {
  __shared__ int sflag;
  const int tid = threadIdx.x;
  if (tid < 64) {
    const float* nf = (const float*)nrm;
    const __hip_bfloat16* nh = (const __hip_bfloat16*)nrm;
    float x = nf[3*tid], y = nf[3*tid+1], z = nf[3*tid+2];
    float ss = x*x + y*y + z*z;
    bool okf = (ss > 0.98f && ss < 1.02f);
    float a = bf(nh[3*tid]), b2 = bf(nh[3*tid+1]), c2 = bf(nh[3*tid+2]);
    float sb = a*a + b2*b2 + c2*c2;
    bool okb = (sb > 0.95f && sb < 1.05f);
    unsigned long long mf = __ballot(okf), mb = __ballot(okb);
    if (tid == 0) {
      sflag = (__popcll(mf) >= __popcll(mb)) ? 1 : 0;
      g_isf32 = sflag;
    }
  }
  __syncthreads();
  const bool f32 = sflag != 0;
  for (int i = tid; i < NB*CH; i += 256) g_gmax[i] = 0u;   // max accumulator (x2 >= 0)
  for (int i = tid; i < 128;  i += 256) g_wts[OW1A + i] = ldf(w1a, i, f32);
  for (int i = tid; i < 32;   i += 256) g_wts[OB1A + i] = ldf(b1a, i, f32);
  for (int i = tid; i < 1024; i += 256) g_wts[OW1B + i] = ldf(w1b, i, f32);
  for (int i = tid; i < 32;   i += 256) g_wts[OB1B + i] = ldf(b1b, i, f32);
  for (int i = tid; i < 1152; i += 256) g_wts[OW2A + i] = ldf(w2a, i, f32);
  for (int i = tid; i < 32;   i += 256) g_wts[OB2A + i] = ldf(b2a, i, f32);
  for (int i = tid; i < 1024; i += 256) g_wts[OW2B + i] = ldf(w2b, i, f32);
  for (int i = tid; i < 32;   i += 256) g_wts[OB2B + i] = ldf(b2b, i, f32);
  for (int i = tid; i < 1280; i += 256) g_wts[OWC  + i] = ldf(wc,  i, f32);
  for (int i = tid; i < 40;   i += 256) g_wts[OBC  + i] = ldf(bc,  i, f32);
}

// ---------------- prep: inputs -> float4 (pos.w = |p|^2 f32, filter only) ----------------
__global__ __launch_bounds__(256) void prep_kernel(const void* __restrict__ pos,
                                                   const void* __restrict__ nrm) {
  const bool f32 = g_isf32 != 0;
  int i = blockIdx.x*256 + threadIdx.x;
  float x = ldf(pos, 3*i, f32), y = ldf(pos, 3*i+1, f32), z = ldf(pos, 3*i+2, f32);
  float sq = x*x + y*y + z*z;
  g_pos4[i] = make_float4(x, y, z, sq);
  float a = ldf(nrm, 3*i, f32), b = ldf(nrm, 3*i+1, f32), c = ldf(nrm, 3*i+2, f32);
  g_nrm4[i] = make_float4(a, b, c, 0.f);
}

// ---------------- kNN: SoA tile, 8 queries/wave, ballot-bisection threshold -------------
// Filter metric d2' = o.w - 2*dot(q,o) (3 fma, q2 = -2q). Pass 1: per-lane min over
// its 64-candidate column, 8 queries per ds_read. Threshold T = exact 17th-smallest
// of the 64 lane-mins, found by 32-step binary search on monotone u32 keys using
// __ballot+popcll -- zero DS-pipe ops (R13's 816 shuffles/wave were the bottleneck).
// Self is unmasked: self d2' = -|q|^2 is the strict global min (Cauchy-Schwarz), so
// >=16 NON-self candidates have d2' <= T. Tf = T + margin >> f32 error => every
// f64-top-16 survives. Pass 2: recompute + sparse collect (wave-private lists).
// f64 rescore (numpy-exact association) + exact lexicographic (d2_f64, idx) rank.
__global__ __launch_bounds__(256) void knn_kernel() {
  __shared__ float sx[NN], sy[NN], sz[NN], sw[NN];  // 65536 B (SoA tile)
  __shared__ unsigned short ilst[32][CAP];          //  6144 B
  __shared__ double dlst[4][CAP];                   //  3072 B
  __shared__ int    cnt[32];
  const int tid  = threadIdx.x;
  const int w    = tid >> 6, lane = tid & 63;
  const int blk  = blockIdx.x;
  const int b    = blk >> 7;                        // 128 blocks per batch
  const int qbw  = ((blk & 127) << 5) | (w << 3);   // first of this wave's 8 queries
  const float4* bp = g_pos4 + b*NN;

  #pragma unroll
  for (int k = 0; k < 16; ++k) {
    int idx = k*256 + tid;
    float4 o = bp[idx];
    sx[idx] = o.x; sy[idx] = o.y; sz[idx] = o.z; sw[idx] = o.w;
  }
  __syncthreads();                                  // the only barrier

  // queries (broadcast LDS reads), pre-negated x(-2)
  float q2x[8], q2y[8], q2z[8];
  #pragma unroll
  for (int qq = 0; qq < 8; ++qq) {
    int qi = qbw + qq;
    q2x[qq] = -2.f*sx[qi]; q2y[qq] = -2.f*sy[qi]; q2z[qq] = -2.f*sz[qi];
  }

  // ---- pass 1: per-lane column mins for 8 queries (self included) ----
  float mn[8];
  #pragma unroll
  for (int qq = 0; qq < 8; ++qq) mn[qq] = BIG;
  #pragma unroll 4
  for (int it = 0; it < 64; ++it) {
    int idx = it*64 + lane;
    float ox = sx[idx], oy = sy[idx], oz = sz[idx], ow = sw[idx];
    #pragma unroll
    for (int qq = 0; qq < 8; ++qq) {
      float d = __builtin_fmaf(q2x[qq], ox,
                __builtin_fmaf(q2y[qq], oy,
                __builtin_fmaf(q2z[qq], oz, ow)));
      mn[qq] = fminf(mn[qq], d);
    }
  }

  // ---- threshold: 17th-smallest lane-min via ballot bisection (no DS ops) ----
  float Tf[8];
  #pragma unroll
  for (int qq = 0; qq < 8; ++qq) {
    unsigned int key = fkey(mn[qq]);
    unsigned int lo = 0u, hi = 0xFFFFFFFFu;
    #pragma unroll 1
    for (int s = 0; s < 32; ++s) {
      unsigned int mid = lo + ((hi - lo) >> 1);
      int c = (int)__popcll(__ballot(key <= mid));
      if (c >= 17) hi = mid; else lo = mid + 1;
    }
    float T = funkey(hi);                           // exact 17th smallest
    Tf[qq] = T + 4e-5f + 1e-5f*fabsf(T);            // margin >> f32 d2' abs error
  }

  if (lane < 8) cnt[(w<<3) | lane] = 0;             // wave-private counters

  // ---- pass 2: recompute + sparse collect into wave-private lists ----
  #pragma unroll 4
  for (int it = 0; it < 64; ++it) {
    int idx = it*64 + lane;
    float ox = sx[idx], oy = sy[idx], oz = sz[idx], ow = sw[idx];
    #pragma unroll
    for (int qq = 0; qq < 8; ++qq) {
      float d = __builtin_fmaf(q2x[qq], ox,
                __builtin_fmaf(q2y[qq], oy,
                __builtin_fmaf(q2z[qq], oz, ow)));
      if (d <= Tf[qq] && idx != qbw + qq) {
        int p = atomicAdd(&cnt[(w<<3)|qq], 1);
        if (p < CAP) ilst[(w<<3)|qq][p] = (unsigned short)idx;
      }
    }
  }

  // ---- per query: f64 rescore (numpy-exact, from LDS tile) + exact rank ----
  #pragma unroll 1
  for (int qq = 0; qq < 8; ++qq) {
    const int qi = qbw + qq;
    const int m = min(cnt[(w<<3)|qq], CAP);
    const double mx = (double)sx[qi], my_ = (double)sy[qi], mz = (double)sz[qi];
    const double sqme = (mx*mx + my_*my_) + mz*mz;
    for (int e = lane; e < m; e += 64) {
      int ci = ilst[(w<<3)|qq][e];
      double ox = (double)sx[ci], oy = (double)sy[ci], oz = (double)sz[ci];
      double sqo = (ox*ox + oy*oy) + oz*oz;
      double dt  = (mx*ox + my_*oy) + mz*oz;
      dlst[w][e] = (sqme + sqo) - 2.0*dt;
    }
    for (int e = lane; e < m; e += 64) {
      double myd = dlst[w][e];
      int myi = ilst[(w<<3)|qq][e];
      int rank = 0;
      for (int o = 0; o < m; ++o) {                 // broadcast LDS reads
        double od = dlst[w][o];
        int oi = ilst[(w<<3)|qq][o];
        rank += (od < myd) || (od == myd && oi < myi);
      }
      if (rank < KK) g_nbr[(b*NN + qi)*KK + rank] = b*NN + myi;
    }
  }
}

// ---------------- conv1: 8 nodes/block, fused u = relu(max(msg1)) @ w2a[0:32] ----------------
__global__ __launch_bounds__(256) void conv1_kernel() {
  __shared__ __align__(16) float fe[136][4];
  __shared__ __align__(16) float h1s[8*SLOTS*CH];
  __shared__ __align__(16) float xs[8][CH];
  const int tid = threadIdx.x;
  const int c = tid & 31;
  const int node0 = blockIdx.x << 3;
  float w1a_c[4], w1b_c[32], w2a_c[32];
  #pragma unroll
  for (int f = 0; f < 4; ++f)  w1a_c[f] = g_wts[OW1A + f*CH + c];
  #pragma unroll
  for (int k = 0; k < 32; ++k) w1b_c[k] = g_wts[OW1B + k*CH + c];
  #pragma unroll
  for (int k = 0; k < 32; ++k) w2a_c[k] = g_wts[OW2A + k*CH + c];
  const float b1a_c = g_wts[OB1A + c], b1b_c = g_wts[OB1B + c];

  if (tid < 136) {
    int ns = tid / 17, slot = tid - ns*17;
    int i = node0 + ns;
    int j = (slot < KK) ? g_nbr[i*KK + slot] : i;   // slot 16 = self-loop
    ppf4(g_pos4[i], g_nrm4[i], g_pos4[j], g_nrm4[j], fe[tid]);
  }
  __syncthreads();
  #pragma unroll
  for (int it = 0; it < 17; ++it) {
    int idx = it*256 + tid;                   // (e, c) with c == tid&31
    int e = idx >> 5;
    float4 f4 = *(const float4*)fe[e];
    float h = b1a_c + f4.x*w1a_c[0] + f4.y*w1a_c[1] + f4.z*w1a_c[2] + f4.w*w1a_c[3];
    h1s[idx] = fmaxf(h, 0.f);
  }
  __syncthreads();
  const int ns = tid >> 5;
  const int i  = node0 + ns;
  float acc = -BIG;
  #pragma unroll
  for (int slot = 0; slot < SLOTS; ++slot) {
    const float* hr = &h1s[(ns*SLOTS + slot)*CH];
    float msg = b1b_c;
    #pragma unroll
    for (int k4 = 0; k4 < 8; ++k4) {
      float4 h4 = *(const float4*)(hr + 4*k4);
      msg += h4.x*w1b_c[4*k4] + h4.y*w1b_c[4*k4+1] + h4.z*w1b_c[4*k4+2] + h4.w*w1b_c[4*k4+3];
    }
    acc = fmaxf(acc, msg);
  }
  xs[ns][c] = fmaxf(acc, 0.f);                // x1 = relu(segment_max)
  __syncthreads();
  float uu = 0.f;
  #pragma unroll
  for (int k4 = 0; k4 < 8; ++k4) {
    float4 x4 = *(const float4*)&xs[ns][4*k4];
    uu += x4.x*w2a_c[4*k4] + x4.y*w2a_c[4*k4+1] + x4.z*w2a_c[4*k4+2] + x4.w*w2a_c[4*k4+3];
  }
  g_u[i*CH + c] = uu;                         // u = x1 @ w2a[0:32,:]
}

// ---------------- conv2 ----------------
__global__ __launch_bounds__(256) void conv2_kernel() {
  __shared__ __align__(16) float fe[136][4];
  __shared__ int jn[136];
  __shared__ __align__(16) float h2s[8*SLOTS*CH];
  const int tid = threadIdx.x;
  const int c = tid & 31;
  const int node0 = blockIdx.x << 3;
  float w2aL_c[4], w2b_c[32];
  #pragma unroll
  for (int f = 0; f < 4; ++f)  w2aL_c[f] = g_wts[OW2A + (CH + f)*CH + c];
  #pragma unroll
  for (int k = 0; k < 32; ++k) w2b_c[k] = g_wts[OW2B + k*CH + c];
  const float b2a_c = g_wts[OB2A + c], b2b_c = g_wts[OB2B + c];

  if (tid < 136) {
    int ns = tid / 17, slot = tid - ns*17;
    int i = node0 + ns;
    int j = (slot < KK) ? g_nbr[i*KK + slot] : i;
    jn[tid] = j;
    ppf4(g_pos4[i], g_nrm4[i], g_pos4[j], g_nrm4[j], fe[tid]);
  }
  __syncthreads();
  #pragma unroll
  for (int it = 0; it < 17; ++it) {
    int idx = it*256 + tid;
    int e = idx >> 5;
    float4 f4 = *(const float4*)fe[e];
    float uv = g_u[jn[e]*CH + c];             // x_j @ w2a[0:32] precomputed
    float h = b2a_c + uv + f4.x*w2aL_c[0] + f4.y*w2aL_c[1] + f4.z*w2aL_c[2] + f4.w*w2aL_c[3];
    h2s[idx] = fmaxf(h, 0.f);
  }
  __syncthreads();
  const int ns = tid >> 5;
  float acc = -BIG;
  #pragma unroll
  for (int slot = 0; slot < SLOTS; ++slot) {
    const float* hr = &h2s[(ns*SLOTS + slot)*CH];
    float msg = b2b_c;
    #pragma unroll
    for (int k4 = 0; k4 < 8; ++k4) {
      float4 h4 = *(const float4*)(hr + 4*k4);
      msg += h4.x*w2b_c[4*k4] + h4.y*w2b_c[4*k4+1] + h4.z*w2b_c[4*k4+2] + h4.w*w2b_c[4*k4+3];
    }
    acc = fmaxf(acc, msg);
  }
  g_x2[(node0 + ns)*CH + c] = fmaxf(acc, 0.f);
}

// ---------------- pmax: 256 blocks, coalesced partial max + device atomicMax ----------------
__global__ __launch_bounds__(256) void pmax_kernel() {
  __shared__ float red[8][CH];
  const int g = blockIdx.x >> 5;              // graph
  const int chunk = blockIdx.x & 31;          // 128 nodes per block
  const int c = threadIdx.x & 31, sub = threadIdx.x >> 5;
  const float* base = g_x2 + (size_t)(g*NN + chunk*128)*CH;
  float mx = 0.f;                             // x2 >= 0 (relu)
  #pragma unroll
  for (int n = 0; n < 16; ++n)
    mx = fmaxf(mx, base[(n*8 + sub)*CH + c]);
  red[sub][c] = mx;
  __syncthreads();
  if (threadIdx.x < CH) {
    float m2 = red[0][c];
    #pragma unroll
    for (int r = 1; r < 8; ++r) m2 = fmaxf(m2, red[r][c]);
    atomicMax(&g_gmax[g*CH + c], __float_as_uint(m2));  // exact for floats >= 0
  }
}

// ---------------- head (float32 output) ----------------
__global__ __launch_bounds__(64) void head_kernel(float* __restrict__ out) {
  const int g = blockIdx.x;
  const int co = threadIdx.x;
  if (co < NCLS) {
    float s = g_wts[OBC + co];
    #pragma unroll
    for (int f = 0; f < CH; ++f)
      s += __uint_as_float(g_gmax[g*CH + f]) * g_wts[OWC + f*NCLS + co];
    out[g*NCLS + co] = s;                     // float32 out (reference dtype)
  }
}

extern "C" void kernel_launch(void* const* d_in, const int* in_sizes, int n_in,
                              void* d_out, int out_size, void* d_ws, size_t ws_size,
                              hipStream_t stream) {
  const void* pos = d_in[0];
  const void* nrm = d_in[1];
  // d_in[2] = batch (int32) -- unused, batches are uniform
  const void* w1a = d_in[3];
  const void* b1a = d_in[4];
  const void* w1b = d_in[5];
  const void* b1b = d_in[6];
  const void* w2a = d_in[7];
  const void* b2a = d_in[8];
  const void* w2b = d_in[9];
  const void* b2b = d_in[10];
  const void* wc  = d_in[11];
  const void* bc  = d_in[12];

  wprep_kernel<<<1,      256, 0, stream>>>(nrm, w1a, b1a, w1b, b1b, w2a, b2a, w2b, b2b, wc, bc);
  prep_kernel <<<MM/256, 256, 0, stream>>>(pos, nrm);
  knn_kernel  <<<MM/32,  256, 0, stream>>>();
  conv1_kernel<<<MM/8,   256, 0, stream>>>();
  conv2_kernel<<<MM/8,   256, 0, stream>>>();
  pmax_kernel <<<NB*32,  256, 0, stream>>>();
  head_kernel <<<NB,     64,  0, stream>>>((float*)d_out);
}

// Round 15
// 231.900 us; speedup vs baseline: 1.9875x; 1.2196x over previous
//
#include <hip/hip_runtime.h>
#include <hip/hip_bf16.h>
#include <math.h>

#define NB 8
#define NN 4096
#define KK 16
#define MM (NB*NN)
#define CH 32
#define SLOTS 17
#define NCLS 40
#define BIG 3.0e38f
#define CAP 96    // survivors ~20-25 with 17th-lane-min threshold (validated R12-R14)

// Weight table offsets (floats)
#define OW1A 0
#define OB1A 128
#define OW1B 160
#define OB1B 1184
#define OW2A 1216
#define OB2A 2368
#define OW2B 2400
#define OB2B 3424
#define OWC  3456
#define OBC  4736
#define NWTS 4776

// Module-global scratch (~11 MB): no assumptions about ws_size.
__device__ float4 g_pos4[MM];
__device__ float4 g_nrm4[MM];
__device__ int    g_nbr[MM*KK];
__device__ float  g_u[MM*CH];
__device__ float  g_x2[MM*CH];
__device__ float  g_wts[NWTS];
__device__ unsigned int g_gmax[NB*CH];
__device__ int    g_isf32;

__device__ __forceinline__ float bf(const __hip_bfloat16 x) { return __bfloat162float(x); }

__device__ __forceinline__ float ldf(const void* p, int i, bool f32) {
  return f32 ? ((const float*)p)[i] : bf(((const __hip_bfloat16*)p)[i]);
}

__device__ __forceinline__ float angf(float ax, float ay, float az,
                                      float bx, float by, float bz) {
  float cx = ay*bz - az*by;
  float cy = az*bx - ax*bz;
  float cz = ax*by - ay*bx;
  float s  = cx*cx + cy*cy + cz*cz;
  float cn = s > 0.f ? sqrtf(s) : 0.f;
  float d  = ax*bx + ay*by + az*bz;
  return (cn > 0.f || d != 0.f) ? atan2f(cn, d) : 0.f;
}

__device__ __forceinline__ void ppf4(const float4 pi, const float4 ni,
                                     const float4 pj, const float4 nj, float* f) {
  float px = pj.x - pi.x, py = pj.y - pi.y, pz = pj.z - pi.z;
  float s = px*px + py*py + pz*pz;
  f[0] = s > 0.f ? sqrtf(s) : 0.f;
  f[1] = angf(ni.x, ni.y, ni.z, px, py, pz);
  f[2] = angf(nj.x, nj.y, nj.z, px, py, pz);
  f[3] = angf(ni.x, ni.y, ni.z, nj.x, nj.y, nj.z);
}

// monotone f32 -> u32 key (order-preserving for all finite floats)
__device__ __forceinline__ unsigned int fkey(float f) {
  unsigned int u = __float_as_uint(f);
  return (u & 0x80000000u) ? ~u : (u | 0x80000000u);
}
__device__ __forceinline__ float funkey(unsigned int k) {
  unsigned int u = (k & 0x80000000u) ? (k ^ 0x80000000u) : ~k;
  return __uint_as_float(u);
}

// ---------------- wprep: parallel dtype vote + weights->fp32 + zero g_gmax ----------------
__global__ __launch_bounds__(256) void wprep_kernel(
    const void* nrm, const void* w1a, const void* b1a, const void* w1b,
    const void* b1b, const void* w2a, const void* b2a, const void* w2b,
    const void* b2b, const void* wc, const void* bc) {
  __shared__ int sflag;
  const int tid = threadIdx.x;
  if (tid < 64) {
    const float* nf = (const float*)nrm;
    const __hip_bfloat16* nh = (const __hip_bfloat16*)nrm;
    float x = nf[3*tid], y = nf[3*tid+1], z = nf[3*tid+2];
    float ss = x*x + y*y + z*z;
    bool okf = (ss > 0.98f && ss < 1.02f);
    float a = bf(nh[3*tid]), b2 = bf(nh[3*tid+1]), c2 = bf(nh[3*tid+2]);
    float sb = a*a + b2*b2 + c2*c2;
    bool okb = (sb > 0.95f && sb < 1.05f);
    unsigned long long mf = __ballot(okf), mb = __ballot(okb);
    if (tid == 0) {
      sflag = (__popcll(mf) >= __popcll(mb)) ? 1 : 0;
      g_isf32 = sflag;
    }
  }
  __syncthreads();
  const bool f32 = sflag != 0;
  for (int i = tid; i < NB*CH; i += 256) g_gmax[i] = 0u;   // max accumulator (x2 >= 0)
  for (int i = tid; i < 128;  i += 256) g_wts[OW1A + i] = ldf(w1a, i, f32);
  for (int i = tid; i < 32;   i += 256) g_wts[OB1A + i] = ldf(b1a, i, f32);
  for (int i = tid; i < 1024; i += 256) g_wts[OW1B + i] = ldf(w1b, i, f32);
  for (int i = tid; i < 32;   i += 256) g_wts[OB1B + i] = ldf(b1b, i, f32);
  for (int i = tid; i < 1152; i += 256) g_wts[OW2A + i] = ldf(w2a, i, f32);
  for (int i = tid; i < 32;   i += 256) g_wts[OB2A + i] = ldf(b2a, i, f32);
  for (int i = tid; i < 1024; i += 256) g_wts[OW2B + i] = ldf(w2b, i, f32);
  for (int i = tid; i < 32;   i += 256) g_wts[OB2B + i] = ldf(b2b, i, f32);
  for (int i = tid; i < 1280; i += 256) g_wts[OWC  + i] = ldf(wc,  i, f32);
  for (int i = tid; i < 40;   i += 256) g_wts[OBC  + i] = ldf(bc,  i, f32);
}

// ---------------- prep: inputs -> float4 (pos.w = |p|^2 f32, filter only) ----------------
__global__ __launch_bounds__(256) void prep_kernel(const void* __restrict__ pos,
                                                   const void* __restrict__ nrm) {
  const bool f32 = g_isf32 != 0;
  int i = blockIdx.x*256 + threadIdx.x;
  float x = ldf(pos, 3*i, f32), y = ldf(pos, 3*i+1, f32), z = ldf(pos, 3*i+2, f32);
  float sq = x*x + y*y + z*z;
  g_pos4[i] = make_float4(x, y, z, sq);
  float a = ldf(nrm, 3*i, f32), b = ldf(nrm, 3*i+1, f32), c = ldf(nrm, 3*i+2, f32);
  g_nrm4[i] = make_float4(a, b, c, 0.f);
}

// ---------------- kNN: 512-thread blocks (8 waves, 64 queries), SoA xyz tile ------------
// Tile amortization: 48 KB xyz tile shared by 8 waves => LDS/block 66.3 KB =>
// 2 blocks/CU x 8 waves = 16 waves/CU (R14: 8). |o|^2 is recomputed per candidate
// (3 VALU, amortized /8 queries) -- bit-identical in both passes; its <=5e-6 abs
// error vs f64 is covered by the 4e-5 margin. Filter d2' = |o|^2 - 2*dot(q,o)
// (3 fma + sq). Threshold T = exact 17th-smallest of the 64 per-lane column-mins
// via 32-step ballot bisection (self included: self d2' = -|q|^2 is the strict
// global min => >=16 non-self candidates <= T). Pass 2 recomputes + collects into
// wave-private lists; f64 rescore (numpy-exact association, from tile components)
// + exact lexicographic (d2_f64, idx) rank. One barrier total.
__global__ __launch_bounds__(512) void knn_kernel() {
  __shared__ float sx[NN], sy[NN], sz[NN];          // 49152 B (SoA xyz tile)
  __shared__ unsigned short ilst[64][CAP];          // 12288 B
  __shared__ double dlst[8][CAP];                   //  6144 B
  __shared__ int    cnt[64];
  const int tid  = threadIdx.x;
  const int w    = tid >> 6, lane = tid & 63;
  const int blk  = blockIdx.x;
  const int b    = blk >> 6;                        // 64 blocks per batch
  const int qbw  = ((blk & 63) << 6) | (w << 3);    // first of this wave's 8 queries
  const float4* bp = g_pos4 + b*NN;

  #pragma unroll
  for (int k = 0; k < 8; ++k) {
    int idx = k*512 + tid;
    float4 o = bp[idx];
    sx[idx] = o.x; sy[idx] = o.y; sz[idx] = o.z;
  }
  __syncthreads();                                  // the only barrier

  // queries (broadcast LDS reads), pre-negated x(-2)
  float q2x[8], q2y[8], q2z[8];
  #pragma unroll
  for (int qq = 0; qq < 8; ++qq) {
    int qi = qbw + qq;
    q2x[qq] = -2.f*sx[qi]; q2y[qq] = -2.f*sy[qi]; q2z[qq] = -2.f*sz[qi];
  }

  // ---- pass 1: per-lane column mins for 8 queries (self included) ----
  float mn[8];
  #pragma unroll
  for (int qq = 0; qq < 8; ++qq) mn[qq] = BIG;
  #pragma unroll 4
  for (int it = 0; it < 64; ++it) {
    int idx = it*64 + lane;
    float ox = sx[idx], oy = sy[idx], oz = sz[idx];
    float ow = __builtin_fmaf(oz, oz, __builtin_fmaf(oy, oy, ox*ox));
    #pragma unroll
    for (int qq = 0; qq < 8; ++qq) {
      float d = __builtin_fmaf(q2x[qq], ox,
                __builtin_fmaf(q2y[qq], oy,
                __builtin_fmaf(q2z[qq], oz, ow)));
      mn[qq] = fminf(mn[qq], d);
    }
  }

  // ---- threshold: 17th-smallest lane-min via ballot bisection (no DS ops) ----
  float Tf[8];
  #pragma unroll
  for (int qq = 0; qq < 8; ++qq) {
    unsigned int key = fkey(mn[qq]);
    unsigned int lo = 0u, hi = 0xFFFFFFFFu;
    #pragma unroll 1
    for (int s = 0; s < 32; ++s) {
      unsigned int mid = lo + ((hi - lo) >> 1);
      int c = (int)__popcll(__ballot(key <= mid));
      if (c >= 17) hi = mid; else lo = mid + 1;
    }
    float T = funkey(hi);                           // exact 17th smallest
    Tf[qq] = T + 4e-5f + 1e-5f*fabsf(T);            // margin >> f32 d2' abs error
  }

  if (lane < 8) cnt[(w<<3) | lane] = 0;             // wave-private counters

  // ---- pass 2: recompute + sparse collect into wave-private lists ----
  #pragma unroll 4
  for (int it = 0; it < 64; ++it) {
    int idx = it*64 + lane;
    float ox = sx[idx], oy = sy[idx], oz = sz[idx];
    float ow = __builtin_fmaf(oz, oz, __builtin_fmaf(oy, oy, ox*ox));
    #pragma unroll
    for (int qq = 0; qq < 8; ++qq) {
      float d = __builtin_fmaf(q2x[qq], ox,
                __builtin_fmaf(q2y[qq], oy,
                __builtin_fmaf(q2z[qq], oz, ow)));
      if (d <= Tf[qq] && idx != qbw + qq) {
        int p = atomicAdd(&cnt[(w<<3)|qq], 1);
        if (p < CAP) ilst[(w<<3)|qq][p] = (unsigned short)idx;
      }
    }
  }

  // ---- per query: f64 rescore (numpy-exact, from LDS tile) + exact rank ----
  #pragma unroll 1
  for (int qq = 0; qq < 8; ++qq) {
    const int qi = qbw + qq;
    const int m = min(cnt[(w<<3)|qq], CAP);
    const double mx = (double)sx[qi], my_ = (double)sy[qi], mz = (double)sz[qi];
    const double sqme = (mx*mx + my_*my_) + mz*mz;
    for (int e = lane; e < m; e += 64) {
      int ci = ilst[(w<<3)|qq][e];
      double ox = (double)sx[ci], oy = (double)sy[ci], oz = (double)sz[ci];
      double sqo = (ox*ox + oy*oy) + oz*oz;
      double dt  = (mx*ox + my_*oy) + mz*oz;
      dlst[w][e] = (sqme + sqo) - 2.0*dt;
    }
    for (int e = lane; e < m; e += 64) {
      double myd = dlst[w][e];
      int myi = ilst[(w<<3)|qq][e];
      int rank = 0;
      for (int o = 0; o < m; ++o) {                 // broadcast LDS reads
        double od = dlst[w][o];
        int oi = ilst[(w<<3)|qq][o];
        rank += (od < myd) || (od == myd && oi < myi);
      }
      if (rank < KK) g_nbr[(b*NN + qi)*KK + rank] = b*NN + myi;
    }
  }
}

// ---------------- conv1: 8 nodes/block, fused u = relu(max(msg1)) @ w2a[0:32] ----------------
__global__ __launch_bounds__(256) void conv1_kernel() {
  __shared__ __align__(16) float fe[136][4];
  __shared__ __align__(16) float h1s[8*SLOTS*CH];
  __shared__ __align__(16) float xs[8][CH];
  const int tid = threadIdx.x;
  const int c = tid & 31;
  const int node0 = blockIdx.x << 3;
  float w1a_c[4], w1b_c[32], w2a_c[32];
  #pragma unroll
  for (int f = 0; f < 4; ++f)  w1a_c[f] = g_wts[OW1A + f*CH + c];
  #pragma unroll
  for (int k = 0; k < 32; ++k) w1b_c[k] = g_wts[OW1B + k*CH + c];
  #pragma unroll
  for (int k = 0; k < 32; ++k) w2a_c[k] = g_wts[OW2A + k*CH + c];
  const float b1a_c = g_wts[OB1A + c], b1b_c = g_wts[OB1B + c];

  if (tid < 136) {
    int ns = tid / 17, slot = tid - ns*17;
    int i = node0 + ns;
    int j = (slot < KK) ? g_nbr[i*KK + slot] : i;   // slot 16 = self-loop
    ppf4(g_pos4[i], g_nrm4[i], g_pos4[j], g_nrm4[j], fe[tid]);
  }
  __syncthreads();
  #pragma unroll
  for (int it = 0; it < 17; ++it) {
    int idx = it*256 + tid;                   // (e, c) with c == tid&31
    int e = idx >> 5;
    float4 f4 = *(const float4*)fe[e];
    float h = b1a_c + f4.x*w1a_c[0] + f4.y*w1a_c[1] + f4.z*w1a_c[2] + f4.w*w1a_c[3];
    h1s[idx] = fmaxf(h, 0.f);
  }
  __syncthreads();
  const int ns = tid >> 5;
  const int i  = node0 + ns;
  float acc = -BIG;
  #pragma unroll
  for (int slot = 0; slot < SLOTS; ++slot) {
    const float* hr = &h1s[(ns*SLOTS + slot)*CH];
    float msg = b1b_c;
    #pragma unroll
    for (int k4 = 0; k4 < 8; ++k4) {
      float4 h4 = *(const float4*)(hr + 4*k4);
      msg += h4.x*w1b_c[4*k4] + h4.y*w1b_c[4*k4+1] + h4.z*w1b_c[4*k4+2] + h4.w*w1b_c[4*k4+3];
    }
    acc = fmaxf(acc, msg);
  }
  xs[ns][c] = fmaxf(acc, 0.f);                // x1 = relu(segment_max)
  __syncthreads();
  float uu = 0.f;
  #pragma unroll
  for (int k4 = 0; k4 < 8; ++k4) {
    float4 x4 = *(const float4*)&xs[ns][4*k4];
    uu += x4.x*w2a_c[4*k4] + x4.y*w2a_c[4*k4+1] + x4.z*w2a_c[4*k4+2] + x4.w*w2a_c[4*k4+3];
  }
  g_u[i*CH + c] = uu;                         // u = x1 @ w2a[0:32,:]
}

// ---------------- conv2 ----------------
__global__ __launch_bounds__(256) void conv2_kernel() {
  __shared__ __align__(16) float fe[136][4];
  __shared__ int jn[136];
  __shared__ __align__(16) float h2s[8*SLOTS*CH];
  const int tid = threadIdx.x;
  const int c = tid & 31;
  const int node0 = blockIdx.x << 3;
  float w2aL_c[4], w2b_c[32];
  #pragma unroll
  for (int f = 0; f < 4; ++f)  w2aL_c[f] = g_wts[OW2A + (CH + f)*CH + c];
  #pragma unroll
  for (int k = 0; k < 32; ++k) w2b_c[k] = g_wts[OW2B + k*CH + c];
  const float b2a_c = g_wts[OB2A + c], b2b_c = g_wts[OB2B + c];

  if (tid < 136) {
    int ns = tid / 17, slot = tid - ns*17;
    int i = node0 + ns;
    int j = (slot < KK) ? g_nbr[i*KK + slot] : i;
    jn[tid] = j;
    ppf4(g_pos4[i], g_nrm4[i], g_pos4[j], g_nrm4[j], fe[tid]);
  }
  __syncthreads();
  #pragma unroll
  for (int it = 0; it < 17; ++it) {
    int idx = it*256 + tid;
    int e = idx >> 5;
    float4 f4 = *(const float4*)fe[e];
    float uv = g_u[jn[e]*CH + c];             // x_j @ w2a[0:32] precomputed
    float h = b2a_c + uv + f4.x*w2aL_c[0] + f4.y*w2aL_c[1] + f4.z*w2aL_c[2] + f4.w*w2aL_c[3];
    h2s[idx] = fmaxf(h, 0.f);
  }
  __syncthreads();
  const int ns = tid >> 5;
  float acc = -BIG;
  #pragma unroll
  for (int slot = 0; slot < SLOTS; ++slot) {
    const float* hr = &h2s[(ns*SLOTS + slot)*CH];
    float msg = b2b_c;
    #pragma unroll
    for (int k4 = 0; k4 < 8; ++k4) {
      float4 h4 = *(const float4*)(hr + 4*k4);
      msg += h4.x*w2b_c[4*k4] + h4.y*w2b_c[4*k4+1] + h4.z*w2b_c[4*k4+2] + h4.w*w2b_c[4*k4+3];
    }
    acc = fmaxf(acc, msg);
  }
  g_x2[(node0 + ns)*CH + c] = fmaxf(acc, 0.f);
}

// ---------------- pmax: 256 blocks, coalesced partial max + device atomicMax ----------------
__global__ __launch_bounds__(256) void pmax_kernel() {
  __shared__ float red[8][CH];
  const int g = blockIdx.x >> 5;              // graph
  const int chunk = blockIdx.x & 31;          // 128 nodes per block
  const int c = threadIdx.x & 31, sub = threadIdx.x >> 5;
  const float* base = g_x2 + (size_t)(g*NN + chunk*128)*CH;
  float mx = 0.f;                             // x2 >= 0 (relu)
  #pragma unroll
  for (int n = 0; n < 16; ++n)
    mx = fmaxf(mx, base[(n*8 + sub)*CH + c]);
  red[sub][c] = mx;
  __syncthreads();
  if (threadIdx.x < CH) {
    float m2 = red[0][c];
    #pragma unroll
    for (int r = 1; r < 8; ++r) m2 = fmaxf(m2, red[r][c]);
    atomicMax(&g_gmax[g*CH + c], __float_as_uint(m2));  // exact for floats >= 0
  }
}

// ---------------- head (float32 output) ----------------
__global__ __launch_bounds__(64) void head_kernel(float* __restrict__ out) {
  const int g = blockIdx.x;
  const int co = threadIdx.x;
  if (co < NCLS) {
    float s = g_wts[OBC + co];
    #pragma unroll
    for (int f = 0; f < CH; ++f)
      s += __uint_as_float(g_gmax[g*CH + f]) * g_wts[OWC + f*NCLS + co];
    out[g*NCLS + co] = s;                     // float32 out (reference dtype)
  }
}

extern "C" void kernel_launch(void* const* d_in, const int* in_sizes, int n_in,
                              void* d_out, int out_size, void* d_ws, size_t ws_size,
                              hipStream_t stream) {
  const void* pos = d_in[0];
  const void* nrm = d_in[1];
  // d_in[2] = batch (int32) -- unused, batches are uniform
  const void* w1a = d_in[3];
  const void* b1a = d_in[4];
  const void* w1b = d_in[5];
  const void* b1b = d_in[6];
  const void* w2a = d_in[7];
  const void* b2a = d_in[8];
  const void* w2b = d_in[9];
  const void* b2b = d_in[10];
  const void* wc  = d_in[11];
  const void* bc  = d_in[12];

  wprep_kernel<<<1,      256, 0, stream>>>(nrm, w1a, b1a, w1b, b1b, w2a, b2a, w2b, b2b, wc, bc);
  prep_kernel <<<MM/256, 256, 0, stream>>>(pos, nrm);
  knn_kernel  <<<MM/64,  512, 0, stream>>>();
  conv1_kernel<<<MM/8,   256, 0, stream>>>();
  conv2_kernel<<<MM/8,   256, 0, stream>>>();
  pmax_kernel <<<NB*32,  256, 0, stream>>>();
  head_kernel <<<NB,     64,  0, stream>>>((float*)d_out);
}